// Round 1
// baseline (1070.495 us; speedup 1.0000x reference)
//
#include <hip/hip_runtime.h>
#include <hip/hip_bf16.h>
#include <math.h>

// Problem constants (fixed by the reference)
#define BATCH 16
#define SEQ   2000
#define INSZ  128
#define DMODEL 256
#define NHEAD 2
#define HDIM  128
#define FFDIM 256
#define OUTSZ 64
#define MROWS (BATCH * SEQ)   // 32000

// ---------------------------------------------------------------------------
// Positional-encoding table: pe[s][d], computed in double to match numpy-2.x
// float64 promotion (np.float64 scalar * float32 array -> float64).
// ---------------------------------------------------------------------------
__global__ __launch_bounds__(256) void pe_kernel(float* __restrict__ pe) {
    const int s = blockIdx.x;
    const int n = threadIdx.x;          // 0..255
    const double c = -9.210340371976184 / 256.0;  // -ln(10000)/D
    const double div = exp((double)(n & ~1) * c);
    const double ang = (double)s * div;
    pe[(size_t)s * DMODEL + n] = (float)((n & 1) ? cos(ang) : sin(ang));
}

// ---------------------------------------------------------------------------
// Tiled fp32 GEMM: C[M,N] = A[M,K] @ W[N,K]^T + bias[N]  (+ epilogue)
// EPI: 0 = bias, 1 = bias+relu, 2 = bias + pos-encoding
// BM=128, BN=64, BK=32, 256 threads, 8x4 micro-tile per thread.
// Requires M%128==0, N%64==0, K%32==0 (true for all our shapes).
// ---------------------------------------------------------------------------
template <int EPI>
__global__ __launch_bounds__(256) void gemm_kernel(const float* __restrict__ A,
                                                   const float* __restrict__ W,
                                                   const float* __restrict__ bias,
                                                   const float* __restrict__ pe,
                                                   float* __restrict__ C,
                                                   int M, int N, int K) {
    const int BM = 128, BN = 64, BK = 32;
    __shared__ float As[BK][BM + 4];   // transposed A tile, +4 pad to spread banks
    __shared__ float Ws[BK][BN + 4];   // transposed W tile

    const int tid = threadIdx.x;
    const int m0 = blockIdx.x * BM;
    const int n0 = blockIdx.y * BN;
    const int tm = tid >> 4;   // 0..15
    const int tn = tid & 15;   // 0..15

    float acc[8][4];
    #pragma unroll
    for (int i = 0; i < 8; ++i)
        #pragma unroll
        for (int j = 0; j < 4; ++j) acc[i][j] = 0.f;

    for (int k0 = 0; k0 < K; k0 += BK) {
        // Load A tile: 128x32 floats = 1024 float4, 4 per thread
        #pragma unroll
        for (int l = 0; l < 4; ++l) {
            const int slot = tid + 256 * l;
            const int r = slot >> 3;        // 0..127
            const int c4 = slot & 7;        // 0..7
            const float4 v = *(const float4*)(A + (size_t)(m0 + r) * K + k0 + c4 * 4);
            As[c4 * 4 + 0][r] = v.x;
            As[c4 * 4 + 1][r] = v.y;
            As[c4 * 4 + 2][r] = v.z;
            As[c4 * 4 + 3][r] = v.w;
        }
        // Load W tile: 64x32 floats = 512 float4, 2 per thread
        #pragma unroll
        for (int l = 0; l < 2; ++l) {
            const int slot = tid + 256 * l;
            const int r = slot >> 3;        // 0..63
            const int c4 = slot & 7;
            const float4 v = *(const float4*)(W + (size_t)(n0 + r) * K + k0 + c4 * 4);
            Ws[c4 * 4 + 0][r] = v.x;
            Ws[c4 * 4 + 1][r] = v.y;
            Ws[c4 * 4 + 2][r] = v.z;
            Ws[c4 * 4 + 3][r] = v.w;
        }
        __syncthreads();

        #pragma unroll
        for (int kk = 0; kk < BK; ++kk) {
            const float4 a0 = *(const float4*)&As[kk][tm * 8];
            const float4 a1 = *(const float4*)&As[kk][tm * 8 + 4];
            const float4 w  = *(const float4*)&Ws[kk][tn * 4];
            const float a[8] = {a0.x, a0.y, a0.z, a0.w, a1.x, a1.y, a1.z, a1.w};
            const float wv[4] = {w.x, w.y, w.z, w.w};
            #pragma unroll
            for (int i = 0; i < 8; ++i)
                #pragma unroll
                for (int j = 0; j < 4; ++j) acc[i][j] += a[i] * wv[j];
        }
        __syncthreads();
    }

    #pragma unroll
    for (int i = 0; i < 8; ++i) {
        const int m = m0 + tm * 8 + i;
        const int s = m % SEQ;  // only used for EPI==2
        #pragma unroll
        for (int j = 0; j < 4; ++j) {
            const int n = n0 + tn * 4 + j;
            float v = acc[i][j] + bias[n];
            if (EPI == 1) v = fmaxf(v, 0.f);
            if (EPI == 2) v += pe[(size_t)s * DMODEL + n];
            C[(size_t)m * N + n] = v;
        }
    }
}

// ---------------------------------------------------------------------------
// Banded causal attention. One 128-thread block per (b, h, i).
// qkv layout: [row = b*SEQ+s][768] with q=[0:256), k=[256:512), v=[512:768),
// head h owns [h*128, h*128+128) within each third.
// Row i attends j in [max(0,i-N), i]; N=100 -> cnt<=101<=128 threads.
// ---------------------------------------------------------------------------
__global__ __launch_bounds__(128) void attn_kernel(const float* __restrict__ qkv,
                                                   float* __restrict__ ctx,
                                                   const int* __restrict__ nptr) {
    __shared__ float sQ[HDIM];
    __shared__ float sP[128];
    __shared__ float wred[2];
    __shared__ float wsum[2];

    const int t = threadIdx.x;
    const int bi = blockIdx.x;           // ((b*NHEAD + h) * SEQ) + i, i fastest
    const int i = bi % SEQ;
    const int bh = bi / SEQ;
    const int h = bh & (NHEAD - 1);
    const int b = bh >> 1;
    const int N = *nptr;
    const int jlo = max(0, i - N);
    const int cnt = i - jlo + 1;

    const size_t base = (size_t)b * SEQ * 768;

    // stage scaled q row
    sQ[t] = qkv[base + (size_t)i * 768 + h * HDIM + t] * 0.08838834764831845f; // 1/sqrt(128)
    __syncthreads();

    // scores: thread t handles key j = jlo + t
    float sval = -3.4e38f;
    if (t < cnt) {
        const float4* k4 = (const float4*)(qkv + base + (size_t)(jlo + t) * 768 + DMODEL + h * HDIM);
        float acc = 0.f;
        #pragma unroll
        for (int d = 0; d < HDIM / 4; ++d) {
            const float4 kv = k4[d];
            acc += sQ[4 * d + 0] * kv.x + sQ[4 * d + 1] * kv.y +
                   sQ[4 * d + 2] * kv.z + sQ[4 * d + 3] * kv.w;
        }
        sval = acc;
    }

    // block max (2 waves)
    float m = sval;
    #pragma unroll
    for (int off = 32; off; off >>= 1) m = fmaxf(m, __shfl_xor(m, off));
    if ((t & 63) == 0) wred[t >> 6] = m;
    __syncthreads();
    m = fmaxf(wred[0], wred[1]);

    float p = (t < cnt) ? expf(sval - m) : 0.f;
    sP[t] = p;

    float ssum = p;
    #pragma unroll
    for (int off = 32; off; off >>= 1) ssum += __shfl_xor(ssum, off);
    if ((t & 63) == 0) wsum[t >> 6] = ssum;
    __syncthreads();
    const float inv = 1.f / (wsum[0] + wsum[1]);

    // PV: thread t handles output dim t; coalesced v reads
    float acc = 0.f;
    const float* vcol = qkv + base + (size_t)jlo * 768 + 2 * DMODEL + h * HDIM + t;
    for (int jj = 0; jj < cnt; ++jj) acc += sP[jj] * vcol[(size_t)jj * 768];

    ctx[((size_t)b * SEQ + i) * DMODEL + h * HDIM + t] = acc * inv;
}

// ---------------------------------------------------------------------------
// Fused residual-add + LayerNorm over rows of 256. One 256-thread block/row.
// ---------------------------------------------------------------------------
__global__ __launch_bounds__(256) void add_ln_kernel(const float* __restrict__ X,
                                                     const float* __restrict__ Y,
                                                     const float* __restrict__ g,
                                                     const float* __restrict__ bta,
                                                     float* __restrict__ out) {
    __shared__ float ws1[4];
    __shared__ float ws2[4];
    const int row = blockIdx.x;
    const int t = threadIdx.x;
    const size_t off = (size_t)row * DMODEL + t;
    const float v = X[off] + Y[off];

    float s = v;
    #pragma unroll
    for (int o = 32; o; o >>= 1) s += __shfl_xor(s, o);
    if ((t & 63) == 0) ws1[t >> 6] = s;
    __syncthreads();
    const float mean = (ws1[0] + ws1[1] + ws1[2] + ws1[3]) * (1.f / DMODEL);

    const float d = v - mean;
    float s2 = d * d;
    #pragma unroll
    for (int o = 32; o; o >>= 1) s2 += __shfl_xor(s2, o);
    if ((t & 63) == 0) ws2[t >> 6] = s2;
    __syncthreads();
    const float var = (ws2[0] + ws2[1] + ws2[2] + ws2[3]) * (1.f / DMODEL);

    out[off] = d * rsqrtf(var + 1e-5f) * g[t] + bta[t];
}

// ---------------------------------------------------------------------------
// Launch
// ---------------------------------------------------------------------------
extern "C" void kernel_launch(void* const* d_in, const int* in_sizes, int n_in,
                              void* d_out, int out_size, void* d_ws, size_t ws_size,
                              hipStream_t stream) {
    const float* src       = (const float*)d_in[0];
    const float* enc_w     = (const float*)d_in[1];
    const float* enc_b     = (const float*)d_in[2];
    const float* in_proj_w = (const float*)d_in[3];
    const float* in_proj_b = (const float*)d_in[4];
    const float* out_proj_w= (const float*)d_in[5];
    const float* out_proj_b= (const float*)d_in[6];
    const float* ln1_g     = (const float*)d_in[7];
    const float* ln1_b     = (const float*)d_in[8];
    const float* ff1_w     = (const float*)d_in[9];
    const float* ff1_b     = (const float*)d_in[10];
    const float* ff2_w     = (const float*)d_in[11];
    const float* ff2_b     = (const float*)d_in[12];
    const float* ln2_g     = (const float*)d_in[13];
    const float* ln2_b     = (const float*)d_in[14];
    const float* dec_w     = (const float*)d_in[15];
    const float* dec_b     = (const float*)d_in[16];
    const int*   nptr      = (const int*)d_in[17];

    float* ws = (float*)d_ws;
    // workspace layout (floats); buffers reused once their producer/consumer is done
    float* X    = ws;                       //  8,192,000  (x after encode; later X2)
    float* QKV  = ws + 8192000;             // 24,576,000  (later FFH @QKV, FFO @QKV+8192000)
    float* CTX  = ws + 32768000;            //  8,192,000  (later X1)
    float* AOUT = ws + 40960000;            //  8,192,000
    float* PE   = ws + 49152000;            //    512,000
    float* X1   = CTX;
    float* FFH  = QKV;
    float* FFO  = QKV + 8192000;
    float* X2   = X;
    float* OUT  = (float*)d_out;

    // 1) positional-encoding table
    pe_kernel<<<SEQ, 256, 0, stream>>>(PE);
    // 2) encode: x = src @ enc_w^T + enc_b + pe
    gemm_kernel<2><<<dim3(MROWS / 128, DMODEL / 64), 256, 0, stream>>>(
        src, enc_w, enc_b, PE, X, MROWS, DMODEL, INSZ);
    // 3) qkv = x @ in_proj^T + in_proj_b
    gemm_kernel<0><<<dim3(MROWS / 128, (3 * DMODEL) / 64), 256, 0, stream>>>(
        X, in_proj_w, in_proj_b, nullptr, QKV, MROWS, 3 * DMODEL, DMODEL);
    // 4) banded attention -> ctx
    attn_kernel<<<BATCH * NHEAD * SEQ, 128, 0, stream>>>(QKV, CTX, nptr);
    // 5) attn_out = ctx @ out_proj^T + out_proj_b
    gemm_kernel<0><<<dim3(MROWS / 128, DMODEL / 64), 256, 0, stream>>>(
        CTX, out_proj_w, out_proj_b, nullptr, AOUT, MROWS, DMODEL, DMODEL);
    // 6) x1 = LN(x + attn_out)
    add_ln_kernel<<<MROWS, 256, 0, stream>>>(X, AOUT, ln1_g, ln1_b, X1);
    // 7) ffh = relu(x1 @ ff1^T + ff1_b)
    gemm_kernel<1><<<dim3(MROWS / 128, FFDIM / 64), 256, 0, stream>>>(
        X1, ff1_w, ff1_b, nullptr, FFH, MROWS, FFDIM, DMODEL);
    // 8) ffo = ffh @ ff2^T + ff2_b
    gemm_kernel<0><<<dim3(MROWS / 128, DMODEL / 64), 256, 0, stream>>>(
        FFH, ff2_w, ff2_b, nullptr, FFO, MROWS, DMODEL, FFDIM);
    // 9) x2 = LN(x1 + ffo)
    add_ln_kernel<<<MROWS, 256, 0, stream>>>(X1, FFO, ln2_g, ln2_b, X2);
    // 10) out = x2 @ dec^T + dec_b
    gemm_kernel<0><<<dim3(MROWS / 128, OUTSZ / 64), 256, 0, stream>>>(
        X2, dec_w, dec_b, nullptr, OUT, MROWS, OUTSZ, DMODEL);
}

// Round 4
// 812.177 us; speedup vs baseline: 1.3181x; 1.3181x over previous
//
#include <hip/hip_runtime.h>
#include <hip/hip_bf16.h>
#include <math.h>

// Problem constants (fixed by the reference)
#define BATCH 16
#define SEQ   2000
#define INSZ  128
#define DMODEL 256
#define NHEAD 2
#define HDIM  128
#define FFDIM 256
#define OUTSZ 64
#define MROWS (BATCH * SEQ)   // 32000

// Attention tiling
#define TQ 32
#define TK 160                 // covers band N (<=128) + TQ
#define NQT ((SEQ + TQ - 1) / TQ)   // 63

// ---------------------------------------------------------------------------
// Positional-encoding table (double; matches fp32 ref within fp32 noise)
// ---------------------------------------------------------------------------
__global__ __launch_bounds__(256) void pe_kernel(float* __restrict__ pe) {
    const int s = blockIdx.x;
    const int n = threadIdx.x;          // 0..255
    const double c = -9.210340371976184 / 256.0;  // -ln(10000)/D
    const double div = exp((double)(n & ~1) * c);
    const double ang = (double)s * div;
    pe[(size_t)s * DMODEL + n] = (float)((n & 1) ? cos(ang) : sin(ang));
}

// ---------------------------------------------------------------------------
// Tiled fp32 GEMM: C[M,N] = A[M,K] @ W[N,K]^T + bias[N]  (+ epilogue)
// EPI: 0 = bias, 1 = bias+relu, 2 = bias + pos-encoding
// ---------------------------------------------------------------------------
template <int EPI>
__global__ __launch_bounds__(256) void gemm_kernel(const float* __restrict__ A,
                                                   const float* __restrict__ W,
                                                   const float* __restrict__ bias,
                                                   const float* __restrict__ pe,
                                                   float* __restrict__ C,
                                                   int M, int N, int K) {
    const int BM = 128, BN = 64, BK = 32;
    __shared__ float As[BK][BM + 4];
    __shared__ float Ws[BK][BN + 4];

    const int tid = threadIdx.x;
    const int m0 = blockIdx.x * BM;
    const int n0 = blockIdx.y * BN;
    const int tm = tid >> 4;
    const int tn = tid & 15;

    float acc[8][4];
    #pragma unroll
    for (int i = 0; i < 8; ++i)
        #pragma unroll
        for (int j = 0; j < 4; ++j) acc[i][j] = 0.f;

    for (int k0 = 0; k0 < K; k0 += BK) {
        #pragma unroll
        for (int l = 0; l < 4; ++l) {
            const int slot = tid + 256 * l;
            const int r = slot >> 3;
            const int c4 = slot & 7;
            const float4 v = *(const float4*)(A + (size_t)(m0 + r) * K + k0 + c4 * 4);
            As[c4 * 4 + 0][r] = v.x;
            As[c4 * 4 + 1][r] = v.y;
            As[c4 * 4 + 2][r] = v.z;
            As[c4 * 4 + 3][r] = v.w;
        }
        #pragma unroll
        for (int l = 0; l < 2; ++l) {
            const int slot = tid + 256 * l;
            const int r = slot >> 3;
            const int c4 = slot & 7;
            const float4 v = *(const float4*)(W + (size_t)(n0 + r) * K + k0 + c4 * 4);
            Ws[c4 * 4 + 0][r] = v.x;
            Ws[c4 * 4 + 1][r] = v.y;
            Ws[c4 * 4 + 2][r] = v.z;
            Ws[c4 * 4 + 3][r] = v.w;
        }
        __syncthreads();

        #pragma unroll
        for (int kk = 0; kk < BK; ++kk) {
            const float4 a0 = *(const float4*)&As[kk][tm * 8];
            const float4 a1 = *(const float4*)&As[kk][tm * 8 + 4];
            const float4 w  = *(const float4*)&Ws[kk][tn * 4];
            const float a[8] = {a0.x, a0.y, a0.z, a0.w, a1.x, a1.y, a1.z, a1.w};
            const float wv[4] = {w.x, w.y, w.z, w.w};
            #pragma unroll
            for (int i = 0; i < 8; ++i)
                #pragma unroll
                for (int j = 0; j < 4; ++j) acc[i][j] += a[i] * wv[j];
        }
        __syncthreads();
    }

    #pragma unroll
    for (int i = 0; i < 8; ++i) {
        const int m = m0 + tm * 8 + i;
        const int s = m % SEQ;
        #pragma unroll
        for (int j = 0; j < 4; ++j) {
            const int n = n0 + tn * 4 + j;
            float v = acc[i][j] + bias[n];
            if (EPI == 1) v = fmaxf(v, 0.f);
            if (EPI == 2) v += pe[(size_t)s * DMODEL + n];
            C[(size_t)m * N + n] = v;
        }
    }
}

// ---------------------------------------------------------------------------
// Tiled banded attention (fp32). One 256-thread block per (b, h, 32-query
// tile). Keys [klo, klo+TK) staged chunk-wise (32 dims at a time) in LDS;
// S and PV as register-tiled GEMMs.
// qkv row layout: [768] = q[0:256) k[256:512) v[512:768); head h at h*128.
// ---------------------------------------------------------------------------
__global__ __launch_bounds__(256) void attn_tiled_kernel(const float* __restrict__ qkv,
                                                         float* __restrict__ ctx,
                                                         const int* __restrict__ nptr) {
    __shared__ float KVs[TK][34];      // K (score phase) then V (PV phase), 32-d chunks
    __shared__ float Qs[TQ][34];
    __shared__ float Ps[TQ][162];      // normalized probabilities

    const int tid = threadIdx.x;
    const int tile = blockIdx.x % NQT;
    const int bh   = blockIdx.x / NQT;
    const int h = bh & (NHEAD - 1);
    const int b = bh >> 1;
    const int N = *nptr;               // 100
    const int i0 = tile * TQ;
    const int klo = max(0, i0 - N);

    const size_t base = (size_t)b * SEQ * 768;

    const int tq = tid >> 5;   // 0..7  -> q rows tq*4 .. tq*4+3
    const int tj = tid & 31;   // 0..31 -> j cols tj + 32*jj

    float acc[4][5];
    #pragma unroll
    for (int i = 0; i < 4; ++i)
        #pragma unroll
        for (int jj = 0; jj < 5; ++jj) acc[i][jj] = 0.f;

    // ---- scores: S = (Q/sqrt(hd)) @ K^T over 4 d-chunks ----
    for (int dc = 0; dc < 4; ++dc) {
        const int dbase = h * HDIM + dc * 32;
        // K chunk: TK x 32 floats = 1280 float4, 5 per thread
        #pragma unroll
        for (int l = 0; l < 5; ++l) {
            const int slot = tid + 256 * l;
            const int r = slot >> 3;
            const int c4 = slot & 7;
            const int j = min(klo + r, SEQ - 1);
            const float4 v = *(const float4*)(qkv + base + (size_t)j * 768 + DMODEL + dbase + c4 * 4);
            *(float2*)&KVs[r][c4 * 4]     = make_float2(v.x, v.y);
            *(float2*)&KVs[r][c4 * 4 + 2] = make_float2(v.z, v.w);
        }
        // Q chunk: TQ x 32 floats = 256 float4, 1 per thread; pre-scale
        // (bug fixed: global address now includes + c4*4, matching the LDS slot)
        {
            const int r = tid >> 3;
            const int c4 = tid & 7;
            const int qi = min(i0 + r, SEQ - 1);
            float4 v = *(const float4*)(qkv + base + (size_t)qi * 768 + dbase + c4 * 4);
            const float sc = 0.08838834764831845f;   // 1/sqrt(128)
            *(float2*)&Qs[r][c4 * 4]     = make_float2(v.x * sc, v.y * sc);
            *(float2*)&Qs[r][c4 * 4 + 2] = make_float2(v.z * sc, v.w * sc);
        }
        __syncthreads();

        #pragma unroll
        for (int d = 0; d < 32; d += 2) {
            float2 a[4];
            #pragma unroll
            for (int i = 0; i < 4; ++i) a[i] = *(const float2*)&Qs[tq * 4 + i][d];
            #pragma unroll
            for (int jj = 0; jj < 5; ++jj) {
                const float2 bk = *(const float2*)&KVs[tj + 32 * jj][d];
                #pragma unroll
                for (int i = 0; i < 4; ++i)
                    acc[i][jj] += a[i].x * bk.x + a[i].y * bk.y;
            }
        }
        __syncthreads();
    }

    // ---- masked softmax per q-row (rows live on 32-lane groups) ----
    #pragma unroll
    for (int i = 0; i < 4; ++i) {
        const int q  = tq * 4 + i;
        const int qi = i0 + q;
        float s[5];
        float m = -3.4e38f;
        #pragma unroll
        for (int jj = 0; jj < 5; ++jj) {
            const int ja = klo + tj + 32 * jj;
            const bool ok = (qi < SEQ) && (ja >= qi - N) && (ja <= qi);
            s[jj] = ok ? acc[i][jj] : -3.4e38f;
            m = fmaxf(m, s[jj]);
        }
        #pragma unroll
        for (int off = 16; off; off >>= 1) m = fmaxf(m, __shfl_xor(m, off));
        float sum = 0.f;
        float p[5];
        #pragma unroll
        for (int jj = 0; jj < 5; ++jj) {
            p[jj] = (s[jj] == -3.4e38f) ? 0.f : expf(s[jj] - m);
            sum += p[jj];
        }
        #pragma unroll
        for (int off = 16; off; off >>= 1) sum += __shfl_xor(sum, off);
        const float inv = 1.f / sum;
        #pragma unroll
        for (int jj = 0; jj < 5; ++jj) Ps[q][tj + 32 * jj] = p[jj] * inv;
    }
    __syncthreads();

    // ---- PV: ctx = P @ V over 4 d-chunks; thread = (q row, 4-dim group) ----
    const int pq  = tid >> 3;   // 0..31
    const int pd  = (tid & 7) * 4;
    for (int dc = 0; dc < 4; ++dc) {
        const int dbase = h * HDIM + dc * 32;
        // V chunk load (overwrites K staging)
        #pragma unroll
        for (int l = 0; l < 5; ++l) {
            const int slot = tid + 256 * l;
            const int r = slot >> 3;
            const int c4 = slot & 7;
            const int j = min(klo + r, SEQ - 1);
            const float4 v = *(const float4*)(qkv + base + (size_t)j * 768 + 2 * DMODEL + dbase + c4 * 4);
            *(float2*)&KVs[r][c4 * 4]     = make_float2(v.x, v.y);
            *(float2*)&KVs[r][c4 * 4 + 2] = make_float2(v.z, v.w);
        }
        __syncthreads();

        float a0 = 0.f, a1 = 0.f, a2 = 0.f, a3 = 0.f;
        #pragma unroll 4
        for (int j = 0; j < TK; j += 2) {
            const float2 p2 = *(const float2*)&Ps[pq][j];
            const float2 v0 = *(const float2*)&KVs[j][pd];
            const float2 v1 = *(const float2*)&KVs[j][pd + 2];
            const float2 w0 = *(const float2*)&KVs[j + 1][pd];
            const float2 w1 = *(const float2*)&KVs[j + 1][pd + 2];
            a0 += p2.x * v0.x + p2.y * w0.x;
            a1 += p2.x * v0.y + p2.y * w0.y;
            a2 += p2.x * v1.x + p2.y * w1.x;
            a3 += p2.x * v1.y + p2.y * w1.y;
        }
        __syncthreads();

        const int qi = i0 + pq;
        if (qi < SEQ) {
            float* dst = ctx + ((size_t)b * SEQ + qi) * DMODEL + dbase;
            *(float4*)(dst + pd) = make_float4(a0, a1, a2, a3);
        }
    }
}

// ---------------------------------------------------------------------------
// Fused residual-add + LayerNorm over rows of 256. One 256-thread block/row.
// ---------------------------------------------------------------------------
__global__ __launch_bounds__(256) void add_ln_kernel(const float* __restrict__ X,
                                                     const float* __restrict__ Y,
                                                     const float* __restrict__ g,
                                                     const float* __restrict__ bta,
                                                     float* __restrict__ out) {
    __shared__ float ws1[4];
    __shared__ float ws2[4];
    const int row = blockIdx.x;
    const int t = threadIdx.x;
    const size_t off = (size_t)row * DMODEL + t;
    const float v = X[off] + Y[off];

    float s = v;
    #pragma unroll
    for (int o = 32; o; o >>= 1) s += __shfl_xor(s, o);
    if ((t & 63) == 0) ws1[t >> 6] = s;
    __syncthreads();
    const float mean = (ws1[0] + ws1[1] + ws1[2] + ws1[3]) * (1.f / DMODEL);

    const float d = v - mean;
    float s2 = d * d;
    #pragma unroll
    for (int o = 32; o; o >>= 1) s2 += __shfl_xor(s2, o);
    if ((t & 63) == 0) ws2[t >> 6] = s2;
    __syncthreads();
    const float var = (ws2[0] + ws2[1] + ws2[2] + ws2[3]) * (1.f / DMODEL);

    out[off] = d * rsqrtf(var + 1e-5f) * g[t] + bta[t];
}

// ---------------------------------------------------------------------------
// Launch
// ---------------------------------------------------------------------------
extern "C" void kernel_launch(void* const* d_in, const int* in_sizes, int n_in,
                              void* d_out, int out_size, void* d_ws, size_t ws_size,
                              hipStream_t stream) {
    const float* src       = (const float*)d_in[0];
    const float* enc_w     = (const float*)d_in[1];
    const float* enc_b     = (const float*)d_in[2];
    const float* in_proj_w = (const float*)d_in[3];
    const float* in_proj_b = (const float*)d_in[4];
    const float* out_proj_w= (const float*)d_in[5];
    const float* out_proj_b= (const float*)d_in[6];
    const float* ln1_g     = (const float*)d_in[7];
    const float* ln1_b     = (const float*)d_in[8];
    const float* ff1_w     = (const float*)d_in[9];
    const float* ff1_b     = (const float*)d_in[10];
    const float* ff2_w     = (const float*)d_in[11];
    const float* ff2_b     = (const float*)d_in[12];
    const float* ln2_g     = (const float*)d_in[13];
    const float* ln2_b     = (const float*)d_in[14];
    const float* dec_w     = (const float*)d_in[15];
    const float* dec_b     = (const float*)d_in[16];
    const int*   nptr      = (const int*)d_in[17];

    float* ws = (float*)d_ws;
    float* X    = ws;                       //  8,192,000  (x after encode; later X2)
    float* QKV  = ws + 8192000;             // 24,576,000  (later FFH, FFO)
    float* CTX  = ws + 32768000;            //  8,192,000  (later X1)
    float* AOUT = ws + 40960000;            //  8,192,000
    float* PE   = ws + 49152000;            //    512,000
    float* X1   = CTX;
    float* FFH  = QKV;
    float* FFO  = QKV + 8192000;
    float* X2   = X;
    float* OUT  = (float*)d_out;

    pe_kernel<<<SEQ, 256, 0, stream>>>(PE);
    gemm_kernel<2><<<dim3(MROWS / 128, DMODEL / 64), 256, 0, stream>>>(
        src, enc_w, enc_b, PE, X, MROWS, DMODEL, INSZ);
    gemm_kernel<0><<<dim3(MROWS / 128, (3 * DMODEL) / 64), 256, 0, stream>>>(
        X, in_proj_w, in_proj_b, nullptr, QKV, MROWS, 3 * DMODEL, DMODEL);
    attn_tiled_kernel<<<BATCH * NHEAD * NQT, 256, 0, stream>>>(QKV, CTX, nptr);
    gemm_kernel<0><<<dim3(MROWS / 128, DMODEL / 64), 256, 0, stream>>>(
        CTX, out_proj_w, out_proj_b, nullptr, AOUT, MROWS, DMODEL, DMODEL);
    add_ln_kernel<<<MROWS, 256, 0, stream>>>(X, AOUT, ln1_g, ln1_b, X1);
    gemm_kernel<1><<<dim3(MROWS / 128, FFDIM / 64), 256, 0, stream>>>(
        X1, ff1_w, ff1_b, nullptr, FFH, MROWS, FFDIM, DMODEL);
    gemm_kernel<0><<<dim3(MROWS / 128, DMODEL / 64), 256, 0, stream>>>(
        FFH, ff2_w, ff2_b, nullptr, FFO, MROWS, DMODEL, FFDIM);
    add_ln_kernel<<<MROWS, 256, 0, stream>>>(X1, FFO, ln2_g, ln2_b, X2);
    gemm_kernel<0><<<dim3(MROWS / 128, OUTSZ / 64), 256, 0, stream>>>(
        X2, dec_w, dec_b, nullptr, OUT, MROWS, OUTSZ, DMODEL);
}

// Round 6
// 599.549 us; speedup vs baseline: 1.7855x; 1.3546x over previous
//
#include <hip/hip_runtime.h>
#include <hip/hip_bf16.h>
#include <math.h>

// Problem constants (fixed by the reference)
#define BATCH 16
#define SEQ   2000
#define INSZ  128
#define DMODEL 256
#define NHEAD 2
#define HDIM  128
#define FFDIM 256
#define OUTSZ 64
#define MROWS (BATCH * SEQ)   // 32000

// Attention tiling
#define TQ 32
#define TK 160
#define NQT ((SEQ + TQ - 1) / TQ)   // 63

typedef __attribute__((ext_vector_type(8))) short bf16x8;
typedef __attribute__((ext_vector_type(4))) float f32x4;

static __device__ __forceinline__ short f2bf(float f) {
    union { float f; unsigned int u; } c; c.f = f;
    unsigned int u = c.u + 0x7FFF + ((c.u >> 16) & 1);   // round-to-nearest-even
    return (short)(u >> 16);
}

// ---------------------------------------------------------------------------
// Positional-encoding table (double; matches fp32 ref within fp32 noise)
// ---------------------------------------------------------------------------
__global__ __launch_bounds__(256) void pe_kernel(float* __restrict__ pe) {
    const int s = blockIdx.x;
    const int n = threadIdx.x;
    const double c = -9.210340371976184 / 256.0;  // -ln(10000)/D
    const double div = exp((double)(n & ~1) * c);
    const double ang = (double)s * div;
    pe[(size_t)s * DMODEL + n] = (float)((n & 1) ? cos(ang) : sin(ang));
}

// ---------------------------------------------------------------------------
// Convert all 6 weight matrices fp32 -> bf16 into one packed region.
// Total 442368 elems = 1728 blocks x 256.
// ---------------------------------------------------------------------------
__global__ __launch_bounds__(256) void wconv_kernel(const float* __restrict__ w0, // enc   32768
                                                    const float* __restrict__ w1, // inprj 196608
                                                    const float* __restrict__ w2, // outp  65536
                                                    const float* __restrict__ w3, // ff1   65536
                                                    const float* __restrict__ w4, // ff2   65536
                                                    const float* __restrict__ w5, // dec   16384
                                                    short* __restrict__ dst) {
    int idx = blockIdx.x * 256 + threadIdx.x;
    float v;
    if      (idx < 32768)  v = w0[idx];
    else if (idx < 229376) v = w1[idx - 32768];
    else if (idx < 294912) v = w2[idx - 229376];
    else if (idx < 360448) v = w3[idx - 294912];
    else if (idx < 425984) v = w4[idx - 360448];
    else                   v = w5[idx - 425984];
    dst[idx] = f2bf(v);
}

// ---------------------------------------------------------------------------
// bf16 MFMA GEMM: C[M,N] = A[M,K] @ W[N,K]^T + bias[N]  (+ epilogue)
// A fp32 (converted to bf16 during LDS staging), W pre-converted bf16.
// BM=128 BN=64 BK=64, 256 threads = 4 waves (2x2), wave tile 64x32,
// per wave: 4x2 16x16 frags, mfma_f32_16x16x32_bf16, fp32 accum.
// LDS row stride 72 bf16 = 144 B: 16B-aligned b128 reads, 2-way banks (free).
// EPI: 0 = bias, 1 = bias+relu, 2 = bias + pos-encoding
// ---------------------------------------------------------------------------
template <int EPI>
__global__ __launch_bounds__(256) void gemm_mfma_kernel(const float* __restrict__ A,
                                                        const short* __restrict__ W,
                                                        const float* __restrict__ bias,
                                                        const float* __restrict__ pe,
                                                        float* __restrict__ C,
                                                        int M, int N, int K) {
    __shared__ short As[128][72];
    __shared__ short Ws[64][72];

    const int tid = threadIdx.x;
    const int m0 = blockIdx.x * 128;
    const int n0 = blockIdx.y * 64;
    const int wid = tid >> 6;
    const int wr = wid >> 1;        // 0..1: row half (64 rows)
    const int wc = wid & 1;         // 0..1: col half (32 cols)
    const int lane = tid & 63;
    const int lo = lane & 15;
    const int hi = lane >> 4;

    f32x4 acc[4][2];
    #pragma unroll
    for (int mt = 0; mt < 4; ++mt)
        #pragma unroll
        for (int nt = 0; nt < 2; ++nt) acc[mt][nt] = (f32x4){0.f, 0.f, 0.f, 0.f};

    for (int k0 = 0; k0 < K; k0 += 64) {
        // stage A: 128x64 fp32 -> bf16. 2048 float4, 8 per thread.
        #pragma unroll
        for (int l = 0; l < 8; ++l) {
            const int s = tid + 256 * l;
            const int r = s >> 4;          // 0..127
            const int c4 = s & 15;         // 0..15 (float4 within the 64-k row)
            const float4 v = *(const float4*)(A + (size_t)(m0 + r) * K + k0 + c4 * 4);
            *(short4*)&As[r][c4 * 4] = make_short4(f2bf(v.x), f2bf(v.y), f2bf(v.z), f2bf(v.w));
        }
        // stage W (already bf16): 64x64 shorts = 512 short8, 2 per thread.
        #pragma unroll
        for (int l = 0; l < 2; ++l) {
            const int s = tid + 256 * l;
            const int r = s >> 3;          // 0..63
            const int c8 = s & 7;          // 0..7 (short8 within the 64-k row)
            const bf16x8 v = *(const bf16x8*)(W + (size_t)(n0 + r) * K + k0 + c8 * 8);
            *(bf16x8*)&Ws[r][c8 * 8] = v;
        }
        __syncthreads();

        #pragma unroll
        for (int kk = 0; kk < 2; ++kk) {
            bf16x8 bfr[2];
            #pragma unroll
            for (int nt = 0; nt < 2; ++nt)
                bfr[nt] = *(const bf16x8*)&Ws[wc * 32 + nt * 16 + lo][kk * 32 + hi * 8];
            #pragma unroll
            for (int mt = 0; mt < 4; ++mt) {
                const bf16x8 afr = *(const bf16x8*)&As[wr * 64 + mt * 16 + lo][kk * 32 + hi * 8];
                acc[mt][0] = __builtin_amdgcn_mfma_f32_16x16x32_bf16(afr, bfr[0], acc[mt][0], 0, 0, 0);
                acc[mt][1] = __builtin_amdgcn_mfma_f32_16x16x32_bf16(afr, bfr[1], acc[mt][1], 0, 0, 0);
            }
        }
        __syncthreads();
    }

    // epilogue: C/D frag mapping col=lane&15, row=(lane>>4)*4+reg  [m89]
    #pragma unroll
    for (int nt = 0; nt < 2; ++nt) {
        const int col = n0 + wc * 32 + nt * 16 + lo;
        const float bi = bias[col];
        #pragma unroll
        for (int mt = 0; mt < 4; ++mt) {
            #pragma unroll
            for (int r = 0; r < 4; ++r) {
                const int row = m0 + wr * 64 + mt * 16 + hi * 4 + r;
                float v = acc[mt][nt][r] + bi;
                if (EPI == 1) v = fmaxf(v, 0.f);
                if (EPI == 2) v += pe[(size_t)(row % SEQ) * DMODEL + col];
                C[(size_t)row * N + col] = v;
            }
        }
    }
}

// ---------------------------------------------------------------------------
// Tiled banded attention (fp32), unchanged (287 us measured round 4).
// ---------------------------------------------------------------------------
__global__ __launch_bounds__(256) void attn_tiled_kernel(const float* __restrict__ qkv,
                                                         float* __restrict__ ctx,
                                                         const int* __restrict__ nptr) {
    __shared__ float KVs[TK][34];
    __shared__ float Qs[TQ][34];
    __shared__ float Ps[TQ][162];

    const int tid = threadIdx.x;
    const int tile = blockIdx.x % NQT;
    const int bh   = blockIdx.x / NQT;
    const int h = bh & (NHEAD - 1);
    const int b = bh >> 1;
    const int N = *nptr;               // 100
    const int i0 = tile * TQ;
    const int klo = max(0, i0 - N);

    const size_t base = (size_t)b * SEQ * 768;

    const int tq = tid >> 5;
    const int tj = tid & 31;

    float acc[4][5];
    #pragma unroll
    for (int i = 0; i < 4; ++i)
        #pragma unroll
        for (int jj = 0; jj < 5; ++jj) acc[i][jj] = 0.f;

    for (int dc = 0; dc < 4; ++dc) {
        const int dbase = h * HDIM + dc * 32;
        #pragma unroll
        for (int l = 0; l < 5; ++l) {
            const int slot = tid + 256 * l;
            const int r = slot >> 3;
            const int c4 = slot & 7;
            const int j = min(klo + r, SEQ - 1);
            const float4 v = *(const float4*)(qkv + base + (size_t)j * 768 + DMODEL + dbase + c4 * 4);
            *(float2*)&KVs[r][c4 * 4]     = make_float2(v.x, v.y);
            *(float2*)&KVs[r][c4 * 4 + 2] = make_float2(v.z, v.w);
        }
        {
            const int r = tid >> 3;
            const int c4 = tid & 7;
            const int qi = min(i0 + r, SEQ - 1);
            float4 v = *(const float4*)(qkv + base + (size_t)qi * 768 + dbase + c4 * 4);
            const float sc = 0.08838834764831845f;   // 1/sqrt(128)
            *(float2*)&Qs[r][c4 * 4]     = make_float2(v.x * sc, v.y * sc);
            *(float2*)&Qs[r][c4 * 4 + 2] = make_float2(v.z * sc, v.w * sc);
        }
        __syncthreads();

        #pragma unroll
        for (int d = 0; d < 32; d += 2) {
            float2 a[4];
            #pragma unroll
            for (int i = 0; i < 4; ++i) a[i] = *(const float2*)&Qs[tq * 4 + i][d];
            #pragma unroll
            for (int jj = 0; jj < 5; ++jj) {
                const float2 bk = *(const float2*)&KVs[tj + 32 * jj][d];
                #pragma unroll
                for (int i = 0; i < 4; ++i)
                    acc[i][jj] += a[i].x * bk.x + a[i].y * bk.y;
            }
        }
        __syncthreads();
    }

    #pragma unroll
    for (int i = 0; i < 4; ++i) {
        const int q  = tq * 4 + i;
        const int qi = i0 + q;
        float s[5];
        float m = -3.4e38f;
        #pragma unroll
        for (int jj = 0; jj < 5; ++jj) {
            const int ja = klo + tj + 32 * jj;
            const bool ok = (qi < SEQ) && (ja >= qi - N) && (ja <= qi);
            s[jj] = ok ? acc[i][jj] : -3.4e38f;
            m = fmaxf(m, s[jj]);
        }
        #pragma unroll
        for (int off = 16; off; off >>= 1) m = fmaxf(m, __shfl_xor(m, off));
        float sum = 0.f;
        float p[5];
        #pragma unroll
        for (int jj = 0; jj < 5; ++jj) {
            p[jj] = (s[jj] == -3.4e38f) ? 0.f : expf(s[jj] - m);
            sum += p[jj];
        }
        #pragma unroll
        for (int off = 16; off; off >>= 1) sum += __shfl_xor(sum, off);
        const float inv = 1.f / sum;
        #pragma unroll
        for (int jj = 0; jj < 5; ++jj) Ps[q][tj + 32 * jj] = p[jj] * inv;
    }
    __syncthreads();

    const int pq  = tid >> 3;
    const int pd  = (tid & 7) * 4;
    for (int dc = 0; dc < 4; ++dc) {
        const int dbase = h * HDIM + dc * 32;
        #pragma unroll
        for (int l = 0; l < 5; ++l) {
            const int slot = tid + 256 * l;
            const int r = slot >> 3;
            const int c4 = slot & 7;
            const int j = min(klo + r, SEQ - 1);
            const float4 v = *(const float4*)(qkv + base + (size_t)j * 768 + 2 * DMODEL + dbase + c4 * 4);
            *(float2*)&KVs[r][c4 * 4]     = make_float2(v.x, v.y);
            *(float2*)&KVs[r][c4 * 4 + 2] = make_float2(v.z, v.w);
        }
        __syncthreads();

        float a0 = 0.f, a1 = 0.f, a2 = 0.f, a3 = 0.f;
        #pragma unroll 4
        for (int j = 0; j < TK; j += 2) {
            const float2 p2 = *(const float2*)&Ps[pq][j];
            const float2 v0 = *(const float2*)&KVs[j][pd];
            const float2 v1 = *(const float2*)&KVs[j][pd + 2];
            const float2 w0 = *(const float2*)&KVs[j + 1][pd];
            const float2 w1 = *(const float2*)&KVs[j + 1][pd + 2];
            a0 += p2.x * v0.x + p2.y * w0.x;
            a1 += p2.x * v0.y + p2.y * w0.y;
            a2 += p2.x * v1.x + p2.y * w1.x;
            a3 += p2.x * v1.y + p2.y * w1.y;
        }
        __syncthreads();

        const int qi = i0 + pq;
        if (qi < SEQ) {
            float* dst = ctx + ((size_t)b * SEQ + qi) * DMODEL + dbase;
            *(float4*)(dst + pd) = make_float4(a0, a1, a2, a3);
        }
    }
}

// ---------------------------------------------------------------------------
// Fused residual-add + LayerNorm over rows of 256.
// ---------------------------------------------------------------------------
__global__ __launch_bounds__(256) void add_ln_kernel(const float* __restrict__ X,
                                                     const float* __restrict__ Y,
                                                     const float* __restrict__ g,
                                                     const float* __restrict__ bta,
                                                     float* __restrict__ out) {
    __shared__ float ws1[4];
    __shared__ float ws2[4];
    const int row = blockIdx.x;
    const int t = threadIdx.x;
    const size_t off = (size_t)row * DMODEL + t;
    const float v = X[off] + Y[off];

    float s = v;
    #pragma unroll
    for (int o = 32; o; o >>= 1) s += __shfl_xor(s, o);
    if ((t & 63) == 0) ws1[t >> 6] = s;
    __syncthreads();
    const float mean = (ws1[0] + ws1[1] + ws1[2] + ws1[3]) * (1.f / DMODEL);

    const float d = v - mean;
    float s2 = d * d;
    #pragma unroll
    for (int o = 32; o; o >>= 1) s2 += __shfl_xor(s2, o);
    if ((t & 63) == 0) ws2[t >> 6] = s2;
    __syncthreads();
    const float var = (ws2[0] + ws2[1] + ws2[2] + ws2[3]) * (1.f / DMODEL);

    out[off] = d * rsqrtf(var + 1e-5f) * g[t] + bta[t];
}

// ---------------------------------------------------------------------------
// Launch
// ---------------------------------------------------------------------------
extern "C" void kernel_launch(void* const* d_in, const int* in_sizes, int n_in,
                              void* d_out, int out_size, void* d_ws, size_t ws_size,
                              hipStream_t stream) {
    const float* src       = (const float*)d_in[0];
    const float* enc_w     = (const float*)d_in[1];
    const float* enc_b     = (const float*)d_in[2];
    const float* in_proj_w = (const float*)d_in[3];
    const float* in_proj_b = (const float*)d_in[4];
    const float* out_proj_w= (const float*)d_in[5];
    const float* out_proj_b= (const float*)d_in[6];
    const float* ln1_g     = (const float*)d_in[7];
    const float* ln1_b     = (const float*)d_in[8];
    const float* ff1_w     = (const float*)d_in[9];
    const float* ff1_b     = (const float*)d_in[10];
    const float* ff2_w     = (const float*)d_in[11];
    const float* ff2_b     = (const float*)d_in[12];
    const float* ln2_g     = (const float*)d_in[13];
    const float* ln2_b     = (const float*)d_in[14];
    const float* dec_w     = (const float*)d_in[15];
    const float* dec_b     = (const float*)d_in[16];
    const int*   nptr      = (const int*)d_in[17];

    float* ws = (float*)d_ws;
    float* X    = ws;                       //  8,192,000  (x after encode; later X2)
    float* QKV  = ws + 8192000;             // 24,576,000  (later FFH, FFO)
    float* CTX  = ws + 32768000;            //  8,192,000  (later X1)
    float* AOUT = ws + 40960000;            //  8,192,000
    float* PE   = ws + 49152000;            //    512,000
    short* WB   = (short*)(ws + 49664000);  //    442,368 shorts (bf16 weights)
    float* X1   = CTX;
    float* FFH  = QKV;
    float* FFO  = QKV + 8192000;
    float* X2   = X;
    float* OUT  = (float*)d_out;

    // bf16 weight region offsets (shorts)
    short* enc_wb  = WB;
    short* inp_wb  = WB + 32768;
    short* outp_wb = WB + 229376;
    short* ff1_wb  = WB + 294912;
    short* ff2_wb  = WB + 360448;
    short* dec_wb  = WB + 425984;

    pe_kernel<<<SEQ, 256, 0, stream>>>(PE);
    wconv_kernel<<<1728, 256, 0, stream>>>(enc_w, in_proj_w, out_proj_w,
                                           ff1_w, ff2_w, dec_w, WB);

    gemm_mfma_kernel<2><<<dim3(MROWS / 128, DMODEL / 64), 256, 0, stream>>>(
        src, enc_wb, enc_b, PE, X, MROWS, DMODEL, INSZ);
    gemm_mfma_kernel<0><<<dim3(MROWS / 128, (3 * DMODEL) / 64), 256, 0, stream>>>(
        X, inp_wb, in_proj_b, nullptr, QKV, MROWS, 3 * DMODEL, DMODEL);
    attn_tiled_kernel<<<BATCH * NHEAD * NQT, 256, 0, stream>>>(QKV, CTX, nptr);
    gemm_mfma_kernel<0><<<dim3(MROWS / 128, DMODEL / 64), 256, 0, stream>>>(
        CTX, outp_wb, out_proj_b, nullptr, AOUT, MROWS, DMODEL, DMODEL);
    add_ln_kernel<<<MROWS, 256, 0, stream>>>(X, AOUT, ln1_g, ln1_b, X1);
    gemm_mfma_kernel<1><<<dim3(MROWS / 128, FFDIM / 64), 256, 0, stream>>>(
        X1, ff1_wb, ff1_b, nullptr, FFH, MROWS, FFDIM, DMODEL);
    gemm_mfma_kernel<0><<<dim3(MROWS / 128, DMODEL / 64), 256, 0, stream>>>(
        FFH, ff2_wb, ff2_b, nullptr, FFO, MROWS, DMODEL, FFDIM);
    add_ln_kernel<<<MROWS, 256, 0, stream>>>(X1, FFO, ln2_g, ln2_b, X2);
    gemm_mfma_kernel<0><<<dim3(MROWS / 128, OUTSZ / 64), 256, 0, stream>>>(
        X2, dec_wb, dec_b, nullptr, OUT, MROWS, OUTSZ, DMODEL);
}

// Round 8
// 387.335 us; speedup vs baseline: 2.7637x; 1.5479x over previous
//
#include <hip/hip_runtime.h>
#include <hip/hip_bf16.h>
#include <math.h>

// Problem constants (fixed by the reference)
#define BATCH 16
#define SEQ   2000
#define INSZ  128
#define DMODEL 256
#define NHEAD 2
#define HDIM  128
#define FFDIM 256
#define OUTSZ 64
#define MROWS (BATCH * SEQ)   // 32000

// Attention tiling
#define TQ 32
#define TK 160
#define NQT ((SEQ + TQ - 1) / TQ)   // 63

typedef __attribute__((ext_vector_type(8))) short bf16x8;
typedef __attribute__((ext_vector_type(4))) float f32x4;

static __device__ __forceinline__ short f2bf(float f) {
    union { float f; unsigned int u; } c; c.f = f;
    unsigned int u = c.u + 0x7FFF + ((c.u >> 16) & 1);   // round-to-nearest-even
    return (short)(u >> 16);
}

// ---------------------------------------------------------------------------
// Positional-encoding table (double; matches fp32 ref within fp32 noise)
// ---------------------------------------------------------------------------
__global__ __launch_bounds__(256) void pe_kernel(float* __restrict__ pe) {
    const int s = blockIdx.x;
    const int n = threadIdx.x;
    const double c = -9.210340371976184 / 256.0;  // -ln(10000)/D
    const double div = exp((double)(n & ~1) * c);
    const double ang = (double)s * div;
    pe[(size_t)s * DMODEL + n] = (float)((n & 1) ? cos(ang) : sin(ang));
}

// ---------------------------------------------------------------------------
// Convert all 6 weight matrices fp32 -> bf16 into one packed region.
// ---------------------------------------------------------------------------
__global__ __launch_bounds__(256) void wconv_kernel(const float* __restrict__ w0,
                                                    const float* __restrict__ w1,
                                                    const float* __restrict__ w2,
                                                    const float* __restrict__ w3,
                                                    const float* __restrict__ w4,
                                                    const float* __restrict__ w5,
                                                    short* __restrict__ dst) {
    int idx = blockIdx.x * 256 + threadIdx.x;
    float v;
    if      (idx < 32768)  v = w0[idx];
    else if (idx < 229376) v = w1[idx - 32768];
    else if (idx < 294912) v = w2[idx - 229376];
    else if (idx < 360448) v = w3[idx - 294912];
    else if (idx < 425984) v = w4[idx - 360448];
    else                   v = w5[idx - 425984];
    dst[idx] = f2bf(v);
}

// ---------------------------------------------------------------------------
// bf16 MFMA GEMM (unchanged, measured good round 6).
// ---------------------------------------------------------------------------
template <int EPI>
__global__ __launch_bounds__(256) void gemm_mfma_kernel(const float* __restrict__ A,
                                                        const short* __restrict__ W,
                                                        const float* __restrict__ bias,
                                                        const float* __restrict__ pe,
                                                        float* __restrict__ C,
                                                        int M, int N, int K) {
    __shared__ short As[128][72];
    __shared__ short Ws[64][72];

    const int tid = threadIdx.x;
    const int m0 = blockIdx.x * 128;
    const int n0 = blockIdx.y * 64;
    const int wid = tid >> 6;
    const int wr = wid >> 1;
    const int wc = wid & 1;
    const int lane = tid & 63;
    const int lo = lane & 15;
    const int hi = lane >> 4;

    f32x4 acc[4][2];
    #pragma unroll
    for (int mt = 0; mt < 4; ++mt)
        #pragma unroll
        for (int nt = 0; nt < 2; ++nt) acc[mt][nt] = (f32x4){0.f, 0.f, 0.f, 0.f};

    for (int k0 = 0; k0 < K; k0 += 64) {
        #pragma unroll
        for (int l = 0; l < 8; ++l) {
            const int s = tid + 256 * l;
            const int r = s >> 4;
            const int c4 = s & 15;
            const float4 v = *(const float4*)(A + (size_t)(m0 + r) * K + k0 + c4 * 4);
            *(short4*)&As[r][c4 * 4] = make_short4(f2bf(v.x), f2bf(v.y), f2bf(v.z), f2bf(v.w));
        }
        #pragma unroll
        for (int l = 0; l < 2; ++l) {
            const int s = tid + 256 * l;
            const int r = s >> 3;
            const int c8 = s & 7;
            const bf16x8 v = *(const bf16x8*)(W + (size_t)(n0 + r) * K + k0 + c8 * 8);
            *(bf16x8*)&Ws[r][c8 * 8] = v;
        }
        __syncthreads();

        #pragma unroll
        for (int kk = 0; kk < 2; ++kk) {
            bf16x8 bfr[2];
            #pragma unroll
            for (int nt = 0; nt < 2; ++nt)
                bfr[nt] = *(const bf16x8*)&Ws[wc * 32 + nt * 16 + lo][kk * 32 + hi * 8];
            #pragma unroll
            for (int mt = 0; mt < 4; ++mt) {
                const bf16x8 afr = *(const bf16x8*)&As[wr * 64 + mt * 16 + lo][kk * 32 + hi * 8];
                acc[mt][0] = __builtin_amdgcn_mfma_f32_16x16x32_bf16(afr, bfr[0], acc[mt][0], 0, 0, 0);
                acc[mt][1] = __builtin_amdgcn_mfma_f32_16x16x32_bf16(afr, bfr[1], acc[mt][1], 0, 0, 0);
            }
        }
        __syncthreads();
    }

    #pragma unroll
    for (int nt = 0; nt < 2; ++nt) {
        const int col = n0 + wc * 32 + nt * 16 + lo;
        const float bi = bias[col];
        #pragma unroll
        for (int mt = 0; mt < 4; ++mt) {
            #pragma unroll
            for (int r = 0; r < 4; ++r) {
                const int row = m0 + wr * 64 + mt * 16 + hi * 4 + r;
                float v = acc[mt][nt][r] + bi;
                if (EPI == 1) v = fmaxf(v, 0.f);
                if (EPI == 2) v += pe[(size_t)(row % SEQ) * DMODEL + col];
                C[(size_t)row * N + col] = v;
            }
        }
    }
}

// ---------------------------------------------------------------------------
// MFMA banded attention. One 256-thread block (4 waves) per (b, h, 32-query
// tile). Phase 1: S^T = K @ Q^T (swapped operands: keys = rows -> softmax
// reduction is lane-local + one cross-wave LDS combine). Phase 2: in-register
// masked softmax (local-max trick, ONE barrier). Phase 3: ctx = P @ V with
// V kept row-major [key][dim]; the B-fragment is gathered with 8 scalar LDS
// reads per frag, conflict-free via the ((key>>3)&3)<<4 swizzle.
// LDS: KV 40960 B (K then V) + QP 10240 B (Q then P) + red 512 B = 50.5 KB
// -> 3 blocks/CU. Swizzles: K/Q idx^((row&7)<<3); P idx^((row&3)<<3) (pitch
// 160 not pow2 -> &7 would overflow the row); V idx^(((key>>3)&3)<<4).
// ---------------------------------------------------------------------------
__global__ __launch_bounds__(256, 3) void attn_mfma_kernel(const float* __restrict__ qkv,
                                                           float* __restrict__ ctx,
                                                           const int* __restrict__ nptr) {
    __shared__ short KV[160 * 128];     // K (phase 1) then V (phase 3)
    __shared__ short QP[32 * 160];      // Q pitch 128 (phase 1) then P pitch 160
    __shared__ float redmax[2][32];
    __shared__ float redsum[2][32];

    const int tid = threadIdx.x;
    const int tile = blockIdx.x % NQT;
    const int bh = blockIdx.x / NQT;
    const int h = bh & (NHEAD - 1);
    const int b = bh >> 1;
    const int NN = *nptr;               // 100
    const int i0 = tile * TQ;
    const int klo = max(0, i0 - NN);
    const size_t base = (size_t)b * SEQ * 768;

    const int lane = tid & 63;
    const int wid = tid >> 6;
    const int lo = lane & 15;
    const int hi = lane >> 4;
    const int wm = wid >> 1;            // key half: [wm*80, +80)
    const int wn = wid & 1;             // query half: [wn*16, +16)

    // ---- stage K[160][128] and scaled Q[32][128] as bf16 (swizzled) ----
    for (int l = 0; l < 20; ++l) {
        const int s = tid + 256 * l;
        const int r = s >> 5;
        const int c4 = s & 31;
        const int j = min(klo + r, SEQ - 1);
        const float4 v = *(const float4*)(qkv + base + (size_t)j * 768 + DMODEL + h * HDIM + c4 * 4);
        const int idx = (r * 128 + c4 * 4) ^ ((r & 7) << 3);
        *(short4*)&KV[idx] = make_short4(f2bf(v.x), f2bf(v.y), f2bf(v.z), f2bf(v.w));
    }
    for (int l = 0; l < 4; ++l) {
        const int s = tid + 256 * l;
        const int r = s >> 5;
        const int c4 = s & 31;
        const int qi = min(i0 + r, SEQ - 1);
        const float4 v = *(const float4*)(qkv + base + (size_t)qi * 768 + h * HDIM + c4 * 4);
        const float sc = 0.08838834764831845f;   // 1/sqrt(128)
        const int idx = (r * 128 + c4 * 4) ^ ((r & 7) << 3);
        *(short4*)&QP[idx] = make_short4(f2bf(v.x * sc), f2bf(v.y * sc), f2bf(v.z * sc), f2bf(v.w * sc));
    }
    __syncthreads();   // bar0

    // ---- S^T = K @ Q^T : acc rows = keys, cols = queries ----
    f32x4 sacc[5];
    #pragma unroll
    for (int mf = 0; mf < 5; ++mf) sacc[mf] = (f32x4){0.f, 0.f, 0.f, 0.f};
    #pragma unroll
    for (int ks = 0; ks < 4; ++ks) {
        const int qrow = wn * 16 + lo;
        const bf16x8 qf = *(const bf16x8*)&QP[(qrow * 128 + ks * 32 + hi * 8) ^ ((qrow & 7) << 3)];
        #pragma unroll
        for (int mf = 0; mf < 5; ++mf) {
            const int krow = wm * 80 + mf * 16 + lo;
            const bf16x8 kf = *(const bf16x8*)&KV[(krow * 128 + ks * 32 + hi * 8) ^ ((krow & 7) << 3)];
            sacc[mf] = __builtin_amdgcn_mfma_f32_16x16x32_bf16(kf, qf, sacc[mf], 0, 0, 0);
        }
    }

    // ---- masked softmax, wave-local pass (no barrier yet) ----
    // lane holds: query qq = wn*16+lo, keys wm*80 + mf*16 + hi*4 + r
    const int qq = wn * 16 + lo;
    const int qi = i0 + qq;
    float mxw = -3.4e38f;
    #pragma unroll
    for (int mf = 0; mf < 5; ++mf)
        #pragma unroll
        for (int r = 0; r < 4; ++r) {
            const int ja = klo + wm * 80 + mf * 16 + hi * 4 + r;
            const bool ok = (ja >= qi - NN) && (ja <= qi);
            sacc[mf][r] = ok ? sacc[mf][r] : -3.4e38f;
            mxw = fmaxf(mxw, sacc[mf][r]);
        }
    mxw = fmaxf(mxw, __shfl_xor(mxw, 16));
    mxw = fmaxf(mxw, __shfl_xor(mxw, 32));
    mxw = fmaxf(mxw, -1e30f);   // all-masked half-row: keep exp() at 0, not 1
    float sml = 0.f;
    #pragma unroll
    for (int mf = 0; mf < 5; ++mf)
        #pragma unroll
        for (int r = 0; r < 4; ++r) {
            const float p = expf(sacc[mf][r] - mxw);   // masked -> exp(-3.4e38) = 0
            sacc[mf][r] = p;
            sml += p;
        }
    sml += __shfl_xor(sml, 16);
    sml += __shfl_xor(sml, 32);
    if (hi == 0) { redmax[wm][qq] = mxw; redsum[wm][qq] = sml; }
    __syncthreads();   // bar1: QK^T LDS reads done; red* visible

    // ---- stage V[160][128] (overwrites K; reads were fenced by bar1) ----
    for (int l = 0; l < 20; ++l) {
        const int s = tid + 256 * l;
        const int r = s >> 5;
        const int c4 = s & 31;
        const int j = min(klo + r, SEQ - 1);
        const float4 v = *(const float4*)(qkv + base + (size_t)j * 768 + 2 * DMODEL + h * HDIM + c4 * 4);
        const int idx = (r * 128 + c4 * 4) ^ (((r >> 3) & 3) << 4);
        *(short4*)&KV[idx] = make_short4(f2bf(v.x), f2bf(v.y), f2bf(v.z), f2bf(v.w));
    }

    // ---- combine halves, normalize, write P (overwrites Q region) ----
    {
        const float m0 = redmax[0][qq], m1 = redmax[1][qq];
        const float mx = fmaxf(m0, m1);
        const float tot = redsum[0][qq] * expf(m0 - mx) + redsum[1][qq] * expf(m1 - mx);
        const float fac = expf(mxw - mx) / tot;
        #pragma unroll
        for (int mf = 0; mf < 5; ++mf)
            #pragma unroll
            for (int r = 0; r < 4; ++r) {
                const int key = wm * 80 + mf * 16 + hi * 4 + r;
                QP[(qq * 160 + key) ^ ((qq & 3) << 3)] = f2bf(sacc[mf][r] * fac);
            }
    }
    __syncthreads();   // bar2: P and V visible

    // ---- ctx = P @ V : wave wid owns dims [wid*32, +32) ----
    f32x4 oacc[2][2];
    #pragma unroll
    for (int mf = 0; mf < 2; ++mf)
        #pragma unroll
        for (int nf = 0; nf < 2; ++nf) oacc[mf][nf] = (f32x4){0.f, 0.f, 0.f, 0.f};
    const int dimb = wid * 32;
    #pragma unroll
    for (int ksp = 0; ksp < 5; ++ksp) {
        bf16x8 vf0, vf1;
        #pragma unroll
        for (int j = 0; j < 8; ++j) {
            const int key = ksp * 32 + hi * 8 + j;
            const int x = ((key >> 3) & 3) << 4;
            vf0[j] = KV[(key * 128 + dimb + lo) ^ x];
            vf1[j] = KV[(key * 128 + dimb + 16 + lo) ^ x];
        }
        #pragma unroll
        for (int mf = 0; mf < 2; ++mf) {
            const int prow = mf * 16 + lo;
            const bf16x8 pf = *(const bf16x8*)&QP[(prow * 160 + ksp * 32 + hi * 8) ^ ((prow & 3) << 3)];
            oacc[mf][0] = __builtin_amdgcn_mfma_f32_16x16x32_bf16(pf, vf0, oacc[mf][0], 0, 0, 0);
            oacc[mf][1] = __builtin_amdgcn_mfma_f32_16x16x32_bf16(pf, vf1, oacc[mf][1], 0, 0, 0);
        }
    }
    #pragma unroll
    for (int mf = 0; mf < 2; ++mf)
        #pragma unroll
        for (int r = 0; r < 4; ++r) {
            const int q = mf * 16 + hi * 4 + r;
            if (i0 + q < SEQ) {
                float* dst = ctx + ((size_t)b * SEQ + i0 + q) * DMODEL + h * HDIM + dimb;
                dst[lo]      = oacc[mf][0][r];
                dst[16 + lo] = oacc[mf][1][r];
            }
        }
}

// ---------------------------------------------------------------------------
// Fused residual-add + LayerNorm over rows of 256.
// ---------------------------------------------------------------------------
__global__ __launch_bounds__(256) void add_ln_kernel(const float* __restrict__ X,
                                                     const float* __restrict__ Y,
                                                     const float* __restrict__ g,
                                                     const float* __restrict__ bta,
                                                     float* __restrict__ out) {
    __shared__ float ws1[4];
    __shared__ float ws2[4];
    const int row = blockIdx.x;
    const int t = threadIdx.x;
    const size_t off = (size_t)row * DMODEL + t;
    const float v = X[off] + Y[off];

    float s = v;
    #pragma unroll
    for (int o = 32; o; o >>= 1) s += __shfl_xor(s, o);
    if ((t & 63) == 0) ws1[t >> 6] = s;
    __syncthreads();
    const float mean = (ws1[0] + ws1[1] + ws1[2] + ws1[3]) * (1.f / DMODEL);

    const float d = v - mean;
    float s2 = d * d;
    #pragma unroll
    for (int o = 32; o; o >>= 1) s2 += __shfl_xor(s2, o);
    if ((t & 63) == 0) ws2[t >> 6] = s2;
    __syncthreads();
    const float var = (ws2[0] + ws2[1] + ws2[2] + ws2[3]) * (1.f / DMODEL);

    out[off] = d * rsqrtf(var + 1e-5f) * g[t] + bta[t];
}

// ---------------------------------------------------------------------------
// Launch
// ---------------------------------------------------------------------------
extern "C" void kernel_launch(void* const* d_in, const int* in_sizes, int n_in,
                              void* d_out, int out_size, void* d_ws, size_t ws_size,
                              hipStream_t stream) {
    const float* src       = (const float*)d_in[0];
    const float* enc_w     = (const float*)d_in[1];
    const float* enc_b     = (const float*)d_in[2];
    const float* in_proj_w = (const float*)d_in[3];
    const float* in_proj_b = (const float*)d_in[4];
    const float* out_proj_w= (const float*)d_in[5];
    const float* out_proj_b= (const float*)d_in[6];
    const float* ln1_g     = (const float*)d_in[7];
    const float* ln1_b     = (const float*)d_in[8];
    const float* ff1_w     = (const float*)d_in[9];
    const float* ff1_b     = (const float*)d_in[10];
    const float* ff2_w     = (const float*)d_in[11];
    const float* ff2_b     = (const float*)d_in[12];
    const float* ln2_g     = (const float*)d_in[13];
    const float* ln2_b     = (const float*)d_in[14];
    const float* dec_w     = (const float*)d_in[15];
    const float* dec_b     = (const float*)d_in[16];
    const int*   nptr      = (const int*)d_in[17];

    float* ws = (float*)d_ws;
    float* X    = ws;                       //  8,192,000  (x after encode; later X2)
    float* QKV  = ws + 8192000;             // 24,576,000  (later FFH, FFO)
    float* CTX  = ws + 32768000;            //  8,192,000  (later X1)
    float* AOUT = ws + 40960000;            //  8,192,000
    float* PE   = ws + 49152000;            //    512,000
    short* WB   = (short*)(ws + 49664000);  //    442,368 shorts (bf16 weights)
    float* X1   = CTX;
    float* FFH  = QKV;
    float* FFO  = QKV + 8192000;
    float* X2   = X;
    float* OUT  = (float*)d_out;

    short* enc_wb  = WB;
    short* inp_wb  = WB + 32768;
    short* outp_wb = WB + 229376;
    short* ff1_wb  = WB + 294912;
    short* ff2_wb  = WB + 360448;
    short* dec_wb  = WB + 425984;

    pe_kernel<<<SEQ, 256, 0, stream>>>(PE);
    wconv_kernel<<<1728, 256, 0, stream>>>(enc_w, in_proj_w, out_proj_w,
                                           ff1_w, ff2_w, dec_w, WB);

    gemm_mfma_kernel<2><<<dim3(MROWS / 128, DMODEL / 64), 256, 0, stream>>>(
        src, enc_wb, enc_b, PE, X, MROWS, DMODEL, INSZ);
    gemm_mfma_kernel<0><<<dim3(MROWS / 128, (3 * DMODEL) / 64), 256, 0, stream>>>(
        X, inp_wb, in_proj_b, nullptr, QKV, MROWS, 3 * DMODEL, DMODEL);
    attn_mfma_kernel<<<BATCH * NHEAD * NQT, 256, 0, stream>>>(QKV, CTX, nptr);
    gemm_mfma_kernel<0><<<dim3(MROWS / 128, DMODEL / 64), 256, 0, stream>>>(
        CTX, outp_wb, out_proj_b, nullptr, AOUT, MROWS, DMODEL, DMODEL);
    add_ln_kernel<<<MROWS, 256, 0, stream>>>(X, AOUT, ln1_g, ln1_b, X1);
    gemm_mfma_kernel<1><<<dim3(MROWS / 128, FFDIM / 64), 256, 0, stream>>>(
        X1, ff1_wb, ff1_b, nullptr, FFH, MROWS, FFDIM, DMODEL);
    gemm_mfma_kernel<0><<<dim3(MROWS / 128, DMODEL / 64), 256, 0, stream>>>(
        FFH, ff2_wb, ff2_b, nullptr, FFO, MROWS, DMODEL, FFDIM);
    add_ln_kernel<<<MROWS, 256, 0, stream>>>(X1, FFO, ln2_g, ln2_b, X2);
    gemm_mfma_kernel<0><<<dim3(MROWS / 128, OUTSZ / 64), 256, 0, stream>>>(
        X2, dec_wb, dec_b, nullptr, OUT, MROWS, OUTSZ, DMODEL);
}

// Round 10
// 281.715 us; speedup vs baseline: 3.7999x; 1.3749x over previous
//
#include <hip/hip_runtime.h>
#include <hip/hip_bf16.h>
#include <math.h>

// Problem constants (fixed by the reference)
#define BATCH 16
#define SEQ   2000
#define INSZ  128
#define DMODEL 256
#define NHEAD 2
#define HDIM  128
#define FFDIM 256
#define OUTSZ 64
#define MROWS (BATCH * SEQ)   // 32000

// Attention tiling
#define TQ 32
#define TK 160
#define NQT ((SEQ + TQ - 1) / TQ)   // 63

typedef __attribute__((ext_vector_type(8))) short bf16x8;
typedef __attribute__((ext_vector_type(4))) float f32x4;

static __device__ __forceinline__ short f2bf(float f) {
    union { float f; unsigned int u; } c; c.f = f;
    unsigned int u = c.u + 0x7FFF + ((c.u >> 16) & 1);   // round-to-nearest-even
    return (short)(u >> 16);
}
static __device__ __forceinline__ float bf2f(short s) {
    union { unsigned int u; float f; } c; c.u = ((unsigned int)(unsigned short)s) << 16;
    return c.f;
}

// ---------------------------------------------------------------------------
// Positional-encoding table (double; matches fp32 ref within fp32 noise)
// ---------------------------------------------------------------------------
__global__ __launch_bounds__(256) void pe_kernel(float* __restrict__ pe) {
    const int s = blockIdx.x;
    const int n = threadIdx.x;
    const double c = -9.210340371976184 / 256.0;  // -ln(10000)/D
    const double div = exp((double)(n & ~1) * c);
    const double ang = (double)s * div;
    pe[(size_t)s * DMODEL + n] = (float)((n & 1) ? cos(ang) : sin(ang));
}

// ---------------------------------------------------------------------------
// Weights fp32 -> bf16 (packed). in_proj Q-rows (first 65536 elems of w1)
// pre-scaled by 1/sqrt(128) so attention staging is a pure copy.
// ---------------------------------------------------------------------------
__global__ __launch_bounds__(256) void wconv_kernel(const float* __restrict__ w0,
                                                    const float* __restrict__ w1,
                                                    const float* __restrict__ w2,
                                                    const float* __restrict__ w3,
                                                    const float* __restrict__ w4,
                                                    const float* __restrict__ w5,
                                                    short* __restrict__ dst) {
    int idx = blockIdx.x * 256 + threadIdx.x;
    float v;
    if (idx < 32768) v = w0[idx];
    else if (idx < 229376) {
        const int e = idx - 32768;
        v = w1[e];
        if (e < 65536) v *= 0.08838834764831845f;   // Q rows
    }
    else if (idx < 294912) v = w2[idx - 229376];
    else if (idx < 360448) v = w3[idx - 294912];
    else if (idx < 425984) v = w4[idx - 360448];
    else                   v = w5[idx - 425984];
    dst[idx] = f2bf(v);
}

// qkv bias with Q part pre-scaled (768 floats)
__global__ __launch_bounds__(256) void qkvbias_kernel(const float* __restrict__ b,
                                                      float* __restrict__ dst) {
    const int i = blockIdx.x * 256 + threadIdx.x;   // 3 blocks x 256
    dst[i] = b[i] * (i < 256 ? 0.08838834764831845f : 1.f);
}

// ---------------------------------------------------------------------------
// bf16 MFMA GEMM: C[M,N] = A[M,K] @ W[N,K]^T + bias[N]  (+ epilogue)
// ABF: A already bf16 in global. OBF: write bf16. fp32 accumulate always.
// BM=128 BN=64 BK=64, 4 waves (2x2). LDS row stride 72 (144 B).
// EPI: 0 = bias, 1 = bias+relu, 2 = bias + pos-encoding
// ---------------------------------------------------------------------------
template <int EPI, bool ABF, bool OBF>
__global__ __launch_bounds__(256) void gemm_mfma_kernel(const void* __restrict__ Av,
                                                        const short* __restrict__ W,
                                                        const float* __restrict__ bias,
                                                        const float* __restrict__ pe,
                                                        void* __restrict__ Cv,
                                                        int M, int N, int K) {
    __shared__ short As[128][72];
    __shared__ short Ws[64][72];

    const int tid = threadIdx.x;
    const int m0 = blockIdx.x * 128;
    const int n0 = blockIdx.y * 64;
    const int wid = tid >> 6;
    const int wr = wid >> 1;
    const int wc = wid & 1;
    const int lane = tid & 63;
    const int lo = lane & 15;
    const int hi = lane >> 4;

    f32x4 acc[4][2];
    #pragma unroll
    for (int mt = 0; mt < 4; ++mt)
        #pragma unroll
        for (int nt = 0; nt < 2; ++nt) acc[mt][nt] = (f32x4){0.f, 0.f, 0.f, 0.f};

    for (int k0 = 0; k0 < K; k0 += 64) {
        if (ABF) {
            const short* A = (const short*)Av;
            #pragma unroll
            for (int l = 0; l < 4; ++l) {
                const int s = tid + 256 * l;
                const int r = s >> 3;          // 0..127
                const int c8 = s & 7;          // 0..7
                const bf16x8 v = *(const bf16x8*)(A + (size_t)(m0 + r) * K + k0 + c8 * 8);
                *(bf16x8*)&As[r][c8 * 8] = v;
            }
        } else {
            const float* A = (const float*)Av;
            #pragma unroll
            for (int l = 0; l < 8; ++l) {
                const int s = tid + 256 * l;
                const int r = s >> 4;
                const int c4 = s & 15;
                const float4 v = *(const float4*)(A + (size_t)(m0 + r) * K + k0 + c4 * 4);
                *(short4*)&As[r][c4 * 4] = make_short4(f2bf(v.x), f2bf(v.y), f2bf(v.z), f2bf(v.w));
            }
        }
        #pragma unroll
        for (int l = 0; l < 2; ++l) {
            const int s = tid + 256 * l;
            const int r = s >> 3;
            const int c8 = s & 7;
            const bf16x8 v = *(const bf16x8*)(W + (size_t)(n0 + r) * K + k0 + c8 * 8);
            *(bf16x8*)&Ws[r][c8 * 8] = v;
        }
        __syncthreads();

        #pragma unroll
        for (int kk = 0; kk < 2; ++kk) {
            bf16x8 bfr[2];
            #pragma unroll
            for (int nt = 0; nt < 2; ++nt)
                bfr[nt] = *(const bf16x8*)&Ws[wc * 32 + nt * 16 + lo][kk * 32 + hi * 8];
            #pragma unroll
            for (int mt = 0; mt < 4; ++mt) {
                const bf16x8 afr = *(const bf16x8*)&As[wr * 64 + mt * 16 + lo][kk * 32 + hi * 8];
                acc[mt][0] = __builtin_amdgcn_mfma_f32_16x16x32_bf16(afr, bfr[0], acc[mt][0], 0, 0, 0);
                acc[mt][1] = __builtin_amdgcn_mfma_f32_16x16x32_bf16(afr, bfr[1], acc[mt][1], 0, 0, 0);
            }
        }
        __syncthreads();
    }

    // epilogue: C/D frag mapping col=lane&15, row=(lane>>4)*4+reg  [m89]
    #pragma unroll
    for (int nt = 0; nt < 2; ++nt) {
        const int col = n0 + wc * 32 + nt * 16 + lo;
        const float bi = bias[col];
        #pragma unroll
        for (int mt = 0; mt < 4; ++mt) {
            #pragma unroll
            for (int r = 0; r < 4; ++r) {
                const int row = m0 + wr * 64 + mt * 16 + hi * 4 + r;
                float v = acc[mt][nt][r] + bi;
                if (EPI == 1) v = fmaxf(v, 0.f);
                if (EPI == 2) v += pe[(size_t)(row % SEQ) * DMODEL + col];
                if (OBF) ((short*)Cv)[(size_t)row * N + col] = f2bf(v);
                else     ((float*)Cv)[(size_t)row * N + col] = v;
            }
        }
    }
}

// ---------------------------------------------------------------------------
// MFMA banded attention, bf16 I/O. Structure identical to round-8 kernel
// (measured good); staging is now pure 16B copies (Q-scale folded into
// in_proj weights/bias), ctx written bf16.
// ---------------------------------------------------------------------------
__global__ __launch_bounds__(256, 3) void attn_mfma_kernel(const short* __restrict__ qkv,
                                                           short* __restrict__ ctx,
                                                           const int* __restrict__ nptr) {
    __shared__ short KV[160 * 128];     // K (phase 1) then V (phase 3)
    __shared__ short QP[32 * 160];      // Q pitch 128 (phase 1) then P pitch 160
    __shared__ float redmax[2][32];
    __shared__ float redsum[2][32];

    const int tid = threadIdx.x;
    const int tile = blockIdx.x % NQT;
    const int bh = blockIdx.x / NQT;
    const int h = bh & (NHEAD - 1);
    const int b = bh >> 1;
    const int NN = *nptr;               // 100
    const int i0 = tile * TQ;
    const int klo = max(0, i0 - NN);
    const size_t base = (size_t)b * SEQ * 768;

    const int lane = tid & 63;
    const int wid = tid >> 6;
    const int lo = lane & 15;
    const int hi = lane >> 4;
    const int wm = wid >> 1;            // key half: [wm*80, +80)
    const int wn = wid & 1;             // query half: [wn*16, +16)

    // ---- stage K[160][128] and (pre-scaled) Q[32][128], pure copies ----
    #pragma unroll
    for (int l = 0; l < 10; ++l) {
        const int s = tid + 256 * l;
        const int r = s >> 4;           // 0..159
        const int c8 = s & 15;          // 0..15
        const int j = min(klo + r, SEQ - 1);
        const bf16x8 v = *(const bf16x8*)(qkv + base + (size_t)j * 768 + DMODEL + h * HDIM + c8 * 8);
        *(bf16x8*)&KV[(r * 128 + c8 * 8) ^ ((r & 7) << 3)] = v;
    }
    #pragma unroll
    for (int l = 0; l < 2; ++l) {
        const int s = tid + 256 * l;
        const int r = s >> 4;           // 0..31
        const int c8 = s & 15;
        const int qi = min(i0 + r, SEQ - 1);
        const bf16x8 v = *(const bf16x8*)(qkv + base + (size_t)qi * 768 + h * HDIM + c8 * 8);
        *(bf16x8*)&QP[(r * 128 + c8 * 8) ^ ((r & 7) << 3)] = v;
    }
    __syncthreads();   // bar0

    // ---- S^T = K @ Q^T : acc rows = keys, cols = queries ----
    f32x4 sacc[5];
    #pragma unroll
    for (int mf = 0; mf < 5; ++mf) sacc[mf] = (f32x4){0.f, 0.f, 0.f, 0.f};
    #pragma unroll
    for (int ks = 0; ks < 4; ++ks) {
        const int qrow = wn * 16 + lo;
        const bf16x8 qf = *(const bf16x8*)&QP[(qrow * 128 + ks * 32 + hi * 8) ^ ((qrow & 7) << 3)];
        #pragma unroll
        for (int mf = 0; mf < 5; ++mf) {
            const int krow = wm * 80 + mf * 16 + lo;
            const bf16x8 kf = *(const bf16x8*)&KV[(krow * 128 + ks * 32 + hi * 8) ^ ((krow & 7) << 3)];
            sacc[mf] = __builtin_amdgcn_mfma_f32_16x16x32_bf16(kf, qf, sacc[mf], 0, 0, 0);
        }
    }

    // ---- masked softmax, wave-local pass ----
    const int qq = wn * 16 + lo;
    const int qi = i0 + qq;
    float mxw = -3.4e38f;
    #pragma unroll
    for (int mf = 0; mf < 5; ++mf)
        #pragma unroll
        for (int r = 0; r < 4; ++r) {
            const int ja = klo + wm * 80 + mf * 16 + hi * 4 + r;
            const bool ok = (ja >= qi - NN) && (ja <= qi);
            sacc[mf][r] = ok ? sacc[mf][r] : -3.4e38f;
            mxw = fmaxf(mxw, sacc[mf][r]);
        }
    mxw = fmaxf(mxw, __shfl_xor(mxw, 16));
    mxw = fmaxf(mxw, __shfl_xor(mxw, 32));
    mxw = fmaxf(mxw, -1e30f);   // all-masked half-row: keep exp() at 0, not 1
    float sml = 0.f;
    #pragma unroll
    for (int mf = 0; mf < 5; ++mf)
        #pragma unroll
        for (int r = 0; r < 4; ++r) {
            const float p = expf(sacc[mf][r] - mxw);
            sacc[mf][r] = p;
            sml += p;
        }
    sml += __shfl_xor(sml, 16);
    sml += __shfl_xor(sml, 32);
    if (hi == 0) { redmax[wm][qq] = mxw; redsum[wm][qq] = sml; }
    __syncthreads();   // bar1

    // ---- stage V[160][128] (overwrites K) ----
    #pragma unroll
    for (int l = 0; l < 10; ++l) {
        const int s = tid + 256 * l;
        const int r = s >> 4;
        const int c8 = s & 15;
        const int j = min(klo + r, SEQ - 1);
        const bf16x8 v = *(const bf16x8*)(qkv + base + (size_t)j * 768 + 2 * DMODEL + h * HDIM + c8 * 8);
        *(bf16x8*)&KV[(r * 128 + c8 * 8) ^ (((r >> 3) & 3) << 4)] = v;
    }

    // ---- combine halves, normalize, write P ----
    {
        const float m0 = redmax[0][qq], m1 = redmax[1][qq];
        const float mx = fmaxf(m0, m1);
        const float tot = redsum[0][qq] * expf(m0 - mx) + redsum[1][qq] * expf(m1 - mx);
        const float fac = expf(mxw - mx) / tot;
        #pragma unroll
        for (int mf = 0; mf < 5; ++mf)
            #pragma unroll
            for (int r = 0; r < 4; ++r) {
                const int key = wm * 80 + mf * 16 + hi * 4 + r;
                QP[(qq * 160 + key) ^ ((qq & 3) << 3)] = f2bf(sacc[mf][r] * fac);
            }
    }
    __syncthreads();   // bar2

    // ---- ctx = P @ V : wave wid owns dims [wid*32, +32) ----
    f32x4 oacc[2][2];
    #pragma unroll
    for (int mf = 0; mf < 2; ++mf)
        #pragma unroll
        for (int nf = 0; nf < 2; ++nf) oacc[mf][nf] = (f32x4){0.f, 0.f, 0.f, 0.f};
    const int dimb = wid * 32;
    #pragma unroll
    for (int ksp = 0; ksp < 5; ++ksp) {
        bf16x8 vf0, vf1;
        #pragma unroll
        for (int j = 0; j < 8; ++j) {
            const int key = ksp * 32 + hi * 8 + j;
            const int x = ((key >> 3) & 3) << 4;
            vf0[j] = KV[(key * 128 + dimb + lo) ^ x];
            vf1[j] = KV[(key * 128 + dimb + 16 + lo) ^ x];
        }
        #pragma unroll
        for (int mf = 0; mf < 2; ++mf) {
            const int prow = mf * 16 + lo;
            const bf16x8 pf = *(const bf16x8*)&QP[(prow * 160 + ksp * 32 + hi * 8) ^ ((prow & 3) << 3)];
            oacc[mf][0] = __builtin_amdgcn_mfma_f32_16x16x32_bf16(pf, vf0, oacc[mf][0], 0, 0, 0);
            oacc[mf][1] = __builtin_amdgcn_mfma_f32_16x16x32_bf16(pf, vf1, oacc[mf][1], 0, 0, 0);
        }
    }
    #pragma unroll
    for (int mf = 0; mf < 2; ++mf)
        #pragma unroll
        for (int r = 0; r < 4; ++r) {
            const int q = mf * 16 + hi * 4 + r;
            if (i0 + q < SEQ) {
                short* dst = ctx + ((size_t)b * SEQ + i0 + q) * DMODEL + h * HDIM + dimb;
                dst[lo]      = f2bf(oacc[mf][0][r]);
                dst[16 + lo] = f2bf(oacc[mf][1][r]);
            }
        }
}

// ---------------------------------------------------------------------------
// Fused residual-add + LayerNorm, bf16 in / bf16 out, fp32 math.
// ---------------------------------------------------------------------------
__global__ __launch_bounds__(256) void add_ln_kernel(const short* __restrict__ X,
                                                     const short* __restrict__ Y,
                                                     const float* __restrict__ g,
                                                     const float* __restrict__ bta,
                                                     short* __restrict__ out) {
    __shared__ float ws1[4];
    __shared__ float ws2[4];
    const int row = blockIdx.x;
    const int t = threadIdx.x;
    const size_t off = (size_t)row * DMODEL + t;
    const float v = bf2f(X[off]) + bf2f(Y[off]);

    float s = v;
    #pragma unroll
    for (int o = 32; o; o >>= 1) s += __shfl_xor(s, o);
    if ((t & 63) == 0) ws1[t >> 6] = s;
    __syncthreads();
    const float mean = (ws1[0] + ws1[1] + ws1[2] + ws1[3]) * (1.f / DMODEL);

    const float d = v - mean;
    float s2 = d * d;
    #pragma unroll
    for (int o = 32; o; o >>= 1) s2 += __shfl_xor(s2, o);
    if ((t & 63) == 0) ws2[t >> 6] = s2;
    __syncthreads();
    const float var = (ws2[0] + ws2[1] + ws2[2] + ws2[3]) * (1.f / DMODEL);

    out[off] = f2bf(d * rsqrtf(var + 1e-5f) * g[t] + bta[t]);
}

// ---------------------------------------------------------------------------
// Launch
// ---------------------------------------------------------------------------
extern "C" void kernel_launch(void* const* d_in, const int* in_sizes, int n_in,
                              void* d_out, int out_size, void* d_ws, size_t ws_size,
                              hipStream_t stream) {
    const float* src       = (const float*)d_in[0];
    const float* enc_w     = (const float*)d_in[1];
    const float* enc_b     = (const float*)d_in[2];
    const float* in_proj_w = (const float*)d_in[3];
    const float* in_proj_b = (const float*)d_in[4];
    const float* out_proj_w= (const float*)d_in[5];
    const float* out_proj_b= (const float*)d_in[6];
    const float* ln1_g     = (const float*)d_in[7];
    const float* ln1_b     = (const float*)d_in[8];
    const float* ff1_w     = (const float*)d_in[9];
    const float* ff1_b     = (const float*)d_in[10];
    const float* ff2_w     = (const float*)d_in[11];
    const float* ff2_b     = (const float*)d_in[12];
    const float* ln2_g     = (const float*)d_in[13];
    const float* ln2_b     = (const float*)d_in[14];
    const float* dec_w     = (const float*)d_in[15];
    const float* dec_b     = (const float*)d_in[16];
    const int*   nptr      = (const int*)d_in[17];

    // workspace layout (shorts for bf16 activations)
    short* SW   = (short*)d_ws;
    short* X    = SW;                   //  8,192,000 shorts (encode out; later X2)
    short* QKV  = SW + 8192000;         // 24,576,000 (later FFH, FFO)
    short* CTX  = SW + 32768000;        //  8,192,000 (later X1)
    short* AOUT = SW + 40960000;        //  8,192,000
    float* PE   = (float*)(SW + 49152000);   // 512,000 floats
    short* WB   = SW + 50176000;        //   442,368 shorts (bf16 weights)
    float* QKVB = (float*)(SW + 50618368);   // 768 floats (scaled qkv bias)
    short* X1   = CTX;
    short* FFH  = QKV;
    short* FFO  = QKV + 8192000;
    short* X2   = X;
    float* OUT  = (float*)d_out;

    short* enc_wb  = WB;
    short* inp_wb  = WB + 32768;
    short* outp_wb = WB + 229376;
    short* ff1_wb  = WB + 294912;
    short* ff2_wb  = WB + 360448;
    short* dec_wb  = WB + 425984;

    pe_kernel<<<SEQ, 256, 0, stream>>>(PE);
    wconv_kernel<<<1728, 256, 0, stream>>>(enc_w, in_proj_w, out_proj_w,
                                           ff1_w, ff2_w, dec_w, WB);
    qkvbias_kernel<<<3, 256, 0, stream>>>(in_proj_b, QKVB);

    gemm_mfma_kernel<2, false, true><<<dim3(MROWS / 128, DMODEL / 64), 256, 0, stream>>>(
        src, enc_wb, enc_b, PE, X, MROWS, DMODEL, INSZ);
    gemm_mfma_kernel<0, true, true><<<dim3(MROWS / 128, (3 * DMODEL) / 64), 256, 0, stream>>>(
        X, inp_wb, QKVB, nullptr, QKV, MROWS, 3 * DMODEL, DMODEL);
    attn_mfma_kernel<<<BATCH * NHEAD * NQT, 256, 0, stream>>>(QKV, CTX, nptr);
    gemm_mfma_kernel<0, true, true><<<dim3(MROWS / 128, DMODEL / 64), 256, 0, stream>>>(
        CTX, outp_wb, out_proj_b, nullptr, AOUT, MROWS, DMODEL, DMODEL);
    add_ln_kernel<<<MROWS, 256, 0, stream>>>(X, AOUT, ln1_g, ln1_b, X1);
    gemm_mfma_kernel<1, true, true><<<dim3(MROWS / 128, FFDIM / 64), 256, 0, stream>>>(
        X1, ff1_wb, ff1_b, nullptr, FFH, MROWS, FFDIM, DMODEL);
    gemm_mfma_kernel<0, true, true><<<dim3(MROWS / 128, DMODEL / 64), 256, 0, stream>>>(
        FFH, ff2_wb, ff2_b, nullptr, FFO, MROWS, DMODEL, FFDIM);
    add_ln_kernel<<<MROWS, 256, 0, stream>>>(X1, FFO, ln2_g, ln2_b, X2);
    gemm_mfma_kernel<0, true, false><<<dim3(MROWS / 128, OUTSZ / 64), 256, 0, stream>>>(
        X2, dec_wb, dec_b, nullptr, OUT, MROWS, OUTSZ, DMODEL);
}

// Round 11
// 237.416 us; speedup vs baseline: 4.5089x; 1.1866x over previous
//
#include <hip/hip_runtime.h>
#include <hip/hip_bf16.h>
#include <math.h>

// Problem constants (fixed by the reference)
#define BATCH 16
#define SEQ   2000
#define INSZ  128
#define DMODEL 256
#define NHEAD 2
#define HDIM  128
#define FFDIM 256
#define OUTSZ 64
#define MROWS (BATCH * SEQ)   // 32000

// Attention tiling
#define TQ 32
#define TK 160
#define NQT ((SEQ + TQ - 1) / TQ)   // 63

typedef __attribute__((ext_vector_type(8))) short bf16x8;
typedef __attribute__((ext_vector_type(4))) float f32x4;

static __device__ __forceinline__ short f2bf(float f) {
    union { float f; unsigned int u; } c; c.f = f;
    unsigned int u = c.u + 0x7FFF + ((c.u >> 16) & 1);   // round-to-nearest-even
    return (short)(u >> 16);
}
static __device__ __forceinline__ float bf2f(short s) {
    union { unsigned int u; float f; } c; c.u = ((unsigned int)(unsigned short)s) << 16;
    return c.f;
}

// ---------------------------------------------------------------------------
// Positional-encoding table (double; matches fp32 ref within fp32 noise)
// ---------------------------------------------------------------------------
__global__ __launch_bounds__(256) void pe_kernel(float* __restrict__ pe) {
    const int s = blockIdx.x;
    const int n = threadIdx.x;
    const double c = -9.210340371976184 / 256.0;  // -ln(10000)/D
    const double div = exp((double)(n & ~1) * c);
    const double ang = (double)s * div;
    pe[(size_t)s * DMODEL + n] = (float)((n & 1) ? cos(ang) : sin(ang));
}

// ---------------------------------------------------------------------------
// Weights fp32 -> bf16 (packed). in_proj Q-rows pre-scaled by 1/sqrt(128).
// ---------------------------------------------------------------------------
__global__ __launch_bounds__(256) void wconv_kernel(const float* __restrict__ w0,
                                                    const float* __restrict__ w1,
                                                    const float* __restrict__ w2,
                                                    const float* __restrict__ w3,
                                                    const float* __restrict__ w4,
                                                    const float* __restrict__ w5,
                                                    short* __restrict__ dst) {
    int idx = blockIdx.x * 256 + threadIdx.x;
    float v;
    if (idx < 32768) v = w0[idx];
    else if (idx < 229376) {
        const int e = idx - 32768;
        v = w1[e];
        if (e < 65536) v *= 0.08838834764831845f;   // Q rows
    }
    else if (idx < 294912) v = w2[idx - 229376];
    else if (idx < 360448) v = w3[idx - 294912];
    else if (idx < 425984) v = w4[idx - 360448];
    else                   v = w5[idx - 425984];
    dst[idx] = f2bf(v);
}

// qkv bias with Q part pre-scaled (768 floats)
__global__ __launch_bounds__(256) void qkvbias_kernel(const float* __restrict__ b,
                                                      float* __restrict__ dst) {
    const int i = blockIdx.x * 256 + threadIdx.x;   // 3 blocks x 256
    dst[i] = b[i] * (i < 256 ? 0.08838834764831845f : 1.f);
}

// ---------------------------------------------------------------------------
// bf16 MFMA GEMM: C[M,N] = A[M,K] @ W[N,K]^T + bias[N]  (+ epilogue)
// ABF: A already bf16. OBF: write bf16. fp32 accumulate.
// BM=128 BN=64 BK=64, 4 waves (2x2). EPI: 0=bias, 1=bias+relu, 2=bias+pe.
// ---------------------------------------------------------------------------
template <int EPI, bool ABF, bool OBF>
__global__ __launch_bounds__(256) void gemm_mfma_kernel(const void* __restrict__ Av,
                                                        const short* __restrict__ W,
                                                        const float* __restrict__ bias,
                                                        const float* __restrict__ pe,
                                                        void* __restrict__ Cv,
                                                        int M, int N, int K) {
    __shared__ short As[128][72];
    __shared__ short Ws[64][72];

    const int tid = threadIdx.x;
    const int m0 = blockIdx.x * 128;
    const int n0 = blockIdx.y * 64;
    const int wid = tid >> 6;
    const int wr = wid >> 1;
    const int wc = wid & 1;
    const int lane = tid & 63;
    const int lo = lane & 15;
    const int hi = lane >> 4;

    f32x4 acc[4][2];
    #pragma unroll
    for (int mt = 0; mt < 4; ++mt)
        #pragma unroll
        for (int nt = 0; nt < 2; ++nt) acc[mt][nt] = (f32x4){0.f, 0.f, 0.f, 0.f};

    for (int k0 = 0; k0 < K; k0 += 64) {
        if (ABF) {
            const short* A = (const short*)Av;
            #pragma unroll
            for (int l = 0; l < 4; ++l) {
                const int s = tid + 256 * l;
                const int r = s >> 3;
                const int c8 = s & 7;
                const bf16x8 v = *(const bf16x8*)(A + (size_t)(m0 + r) * K + k0 + c8 * 8);
                *(bf16x8*)&As[r][c8 * 8] = v;
            }
        } else {
            const float* A = (const float*)Av;
            #pragma unroll
            for (int l = 0; l < 8; ++l) {
                const int s = tid + 256 * l;
                const int r = s >> 4;
                const int c4 = s & 15;
                const float4 v = *(const float4*)(A + (size_t)(m0 + r) * K + k0 + c4 * 4);
                *(short4*)&As[r][c4 * 4] = make_short4(f2bf(v.x), f2bf(v.y), f2bf(v.z), f2bf(v.w));
            }
        }
        #pragma unroll
        for (int l = 0; l < 2; ++l) {
            const int s = tid + 256 * l;
            const int r = s >> 3;
            const int c8 = s & 7;
            const bf16x8 v = *(const bf16x8*)(W + (size_t)(n0 + r) * K + k0 + c8 * 8);
            *(bf16x8*)&Ws[r][c8 * 8] = v;
        }
        __syncthreads();

        #pragma unroll
        for (int kk = 0; kk < 2; ++kk) {
            bf16x8 bfr[2];
            #pragma unroll
            for (int nt = 0; nt < 2; ++nt)
                bfr[nt] = *(const bf16x8*)&Ws[wc * 32 + nt * 16 + lo][kk * 32 + hi * 8];
            #pragma unroll
            for (int mt = 0; mt < 4; ++mt) {
                const bf16x8 afr = *(const bf16x8*)&As[wr * 64 + mt * 16 + lo][kk * 32 + hi * 8];
                acc[mt][0] = __builtin_amdgcn_mfma_f32_16x16x32_bf16(afr, bfr[0], acc[mt][0], 0, 0, 0);
                acc[mt][1] = __builtin_amdgcn_mfma_f32_16x16x32_bf16(afr, bfr[1], acc[mt][1], 0, 0, 0);
            }
        }
        __syncthreads();
    }

    #pragma unroll
    for (int nt = 0; nt < 2; ++nt) {
        const int col = n0 + wc * 32 + nt * 16 + lo;
        const float bi = bias[col];
        #pragma unroll
        for (int mt = 0; mt < 4; ++mt) {
            #pragma unroll
            for (int r = 0; r < 4; ++r) {
                const int row = m0 + wr * 64 + mt * 16 + hi * 4 + r;
                float v = acc[mt][nt][r] + bi;
                if (EPI == 1) v = fmaxf(v, 0.f);
                if (EPI == 2) v += pe[(size_t)(row % SEQ) * DMODEL + col];
                if (OBF) ((short*)Cv)[(size_t)row * N + col] = f2bf(v);
                else     ((float*)Cv)[(size_t)row * N + col] = v;
            }
        }
    }
}

// ---------------------------------------------------------------------------
// Fused GEMM + bias + residual-add + LayerNorm (N=256 fixed).
// out[row] = LN(R[row] + A[row] @ W^T + bias) * g + beta, bf16 in/out.
// BM=64, BN=256 (full width -> block owns whole rows), BK=64,
// 256 threads = 4 waves (2 row-halves x 2 col-halves); wave tile 32x128,
// frags mt=2 x nt=8, 64 acc VGPRs. LDS 47 KB -> 3 blocks/CU.
// Row stats: shfl_xor over the 16-lane col group + [64][2] LDS combine.
// In-place safe when out==A (block reads only its own rows first).
// ---------------------------------------------------------------------------
__global__ __launch_bounds__(256) void gemm_ln_kernel(const short* __restrict__ A,
                                                      const short* __restrict__ W,
                                                      const float* __restrict__ bias,
                                                      const short* __restrict__ R,
                                                      const float* __restrict__ g,
                                                      const float* __restrict__ beta,
                                                      short* __restrict__ out,
                                                      int M, int K) {
    __shared__ short As[64][72];
    __shared__ short Ws[256][72];
    __shared__ float rsum[64][2];
    __shared__ float rsq[64][2];

    const int tid = threadIdx.x;
    const int m0 = blockIdx.x * 64;
    const int wid = tid >> 6;
    const int wr = wid >> 1;        // 0..1: row half (32 rows)
    const int wc = wid & 1;         // 0..1: col half (128 cols)
    const int lane = tid & 63;
    const int lo = lane & 15;
    const int hi = lane >> 4;

    f32x4 acc[2][8];
    #pragma unroll
    for (int mt = 0; mt < 2; ++mt)
        #pragma unroll
        for (int nt = 0; nt < 8; ++nt) acc[mt][nt] = (f32x4){0.f, 0.f, 0.f, 0.f};

    for (int k0 = 0; k0 < K; k0 += 64) {
        // stage A 64x64: 512 bf16x8, 2/thread
        #pragma unroll
        for (int l = 0; l < 2; ++l) {
            const int s = tid + 256 * l;
            const int r = s >> 3;
            const int c8 = s & 7;
            *(bf16x8*)&As[r][c8 * 8] = *(const bf16x8*)(A + (size_t)(m0 + r) * K + k0 + c8 * 8);
        }
        // stage W 256x64: 2048 bf16x8, 8/thread
        #pragma unroll
        for (int l = 0; l < 8; ++l) {
            const int s = tid + 256 * l;
            const int r = s >> 3;
            const int c8 = s & 7;
            *(bf16x8*)&Ws[r][c8 * 8] = *(const bf16x8*)(W + (size_t)r * K + k0 + c8 * 8);
        }
        __syncthreads();

        #pragma unroll
        for (int kk = 0; kk < 2; ++kk) {
            bf16x8 bfr[8];
            #pragma unroll
            for (int nt = 0; nt < 8; ++nt)
                bfr[nt] = *(const bf16x8*)&Ws[wc * 128 + nt * 16 + lo][kk * 32 + hi * 8];
            #pragma unroll
            for (int mt = 0; mt < 2; ++mt) {
                const bf16x8 afr = *(const bf16x8*)&As[wr * 32 + mt * 16 + lo][kk * 32 + hi * 8];
                #pragma unroll
                for (int nt = 0; nt < 8; ++nt)
                    acc[mt][nt] = __builtin_amdgcn_mfma_f32_16x16x32_bf16(afr, bfr[nt], acc[mt][nt], 0, 0, 0);
            }
        }
        __syncthreads();
    }

    // hoisted per-col params (col = wc*128 + nt*16 + lo)
    float bi[8], gg[8], bb[8];
    #pragma unroll
    for (int nt = 0; nt < 8; ++nt) {
        const int col = wc * 128 + nt * 16 + lo;
        bi[nt] = bias[col]; gg[nt] = g[col]; bb[nt] = beta[col];
    }

    // val = acc + bias + residual; per-row partial stats
    #pragma unroll
    for (int mt = 0; mt < 2; ++mt) {
        #pragma unroll
        for (int r = 0; r < 4; ++r) {
            const int rl = wr * 32 + mt * 16 + hi * 4 + r;   // local row
            const size_t grow = (size_t)(m0 + rl) * DMODEL;
            float s = 0.f, q = 0.f;
            #pragma unroll
            for (int nt = 0; nt < 8; ++nt) {
                const int col = wc * 128 + nt * 16 + lo;
                float v = acc[mt][nt][r] + bi[nt] + bf2f(R[grow + col]);
                acc[mt][nt][r] = v;
                s += v; q += v * v;
            }
            #pragma unroll
            for (int o = 1; o < 16; o <<= 1) { s += __shfl_xor(s, o); q += __shfl_xor(q, o); }
            if (lo == 0) { rsum[rl][wc] = s; rsq[rl][wc] = q; }
        }
    }
    __syncthreads();

    // normalize + write
    #pragma unroll
    for (int mt = 0; mt < 2; ++mt) {
        #pragma unroll
        for (int r = 0; r < 4; ++r) {
            const int rl = wr * 32 + mt * 16 + hi * 4 + r;
            const float mean = (rsum[rl][0] + rsum[rl][1]) * (1.f / DMODEL);
            const float var = (rsq[rl][0] + rsq[rl][1]) * (1.f / DMODEL) - mean * mean;
            const float rstd = rsqrtf(var + 1e-5f);
            const size_t grow = (size_t)(m0 + rl) * DMODEL;
            #pragma unroll
            for (int nt = 0; nt < 8; ++nt) {
                const int col = wc * 128 + nt * 16 + lo;
                out[grow + col] = f2bf((acc[mt][nt][r] - mean) * rstd * gg[nt] + bb[nt]);
            }
        }
    }
}

// ---------------------------------------------------------------------------
// MFMA banded attention, bf16 I/O (unchanged from round 10, measured good).
// ---------------------------------------------------------------------------
__global__ __launch_bounds__(256, 3) void attn_mfma_kernel(const short* __restrict__ qkv,
                                                           short* __restrict__ ctx,
                                                           const int* __restrict__ nptr) {
    __shared__ short KV[160 * 128];
    __shared__ short QP[32 * 160];
    __shared__ float redmax[2][32];
    __shared__ float redsum[2][32];

    const int tid = threadIdx.x;
    const int tile = blockIdx.x % NQT;
    const int bh = blockIdx.x / NQT;
    const int h = bh & (NHEAD - 1);
    const int b = bh >> 1;
    const int NN = *nptr;               // 100
    const int i0 = tile * TQ;
    const int klo = max(0, i0 - NN);
    const size_t base = (size_t)b * SEQ * 768;

    const int lane = tid & 63;
    const int wid = tid >> 6;
    const int lo = lane & 15;
    const int hi = lane >> 4;
    const int wm = wid >> 1;
    const int wn = wid & 1;

    #pragma unroll
    for (int l = 0; l < 10; ++l) {
        const int s = tid + 256 * l;
        const int r = s >> 4;
        const int c8 = s & 15;
        const int j = min(klo + r, SEQ - 1);
        const bf16x8 v = *(const bf16x8*)(qkv + base + (size_t)j * 768 + DMODEL + h * HDIM + c8 * 8);
        *(bf16x8*)&KV[(r * 128 + c8 * 8) ^ ((r & 7) << 3)] = v;
    }
    #pragma unroll
    for (int l = 0; l < 2; ++l) {
        const int s = tid + 256 * l;
        const int r = s >> 4;
        const int c8 = s & 15;
        const int qi = min(i0 + r, SEQ - 1);
        const bf16x8 v = *(const bf16x8*)(qkv + base + (size_t)qi * 768 + h * HDIM + c8 * 8);
        *(bf16x8*)&QP[(r * 128 + c8 * 8) ^ ((r & 7) << 3)] = v;
    }
    __syncthreads();   // bar0

    f32x4 sacc[5];
    #pragma unroll
    for (int mf = 0; mf < 5; ++mf) sacc[mf] = (f32x4){0.f, 0.f, 0.f, 0.f};
    #pragma unroll
    for (int ks = 0; ks < 4; ++ks) {
        const int qrow = wn * 16 + lo;
        const bf16x8 qf = *(const bf16x8*)&QP[(qrow * 128 + ks * 32 + hi * 8) ^ ((qrow & 7) << 3)];
        #pragma unroll
        for (int mf = 0; mf < 5; ++mf) {
            const int krow = wm * 80 + mf * 16 + lo;
            const bf16x8 kf = *(const bf16x8*)&KV[(krow * 128 + ks * 32 + hi * 8) ^ ((krow & 7) << 3)];
            sacc[mf] = __builtin_amdgcn_mfma_f32_16x16x32_bf16(kf, qf, sacc[mf], 0, 0, 0);
        }
    }

    const int qq = wn * 16 + lo;
    const int qi = i0 + qq;
    float mxw = -3.4e38f;
    #pragma unroll
    for (int mf = 0; mf < 5; ++mf)
        #pragma unroll
        for (int r = 0; r < 4; ++r) {
            const int ja = klo + wm * 80 + mf * 16 + hi * 4 + r;
            const bool ok = (ja >= qi - NN) && (ja <= qi);
            sacc[mf][r] = ok ? sacc[mf][r] : -3.4e38f;
            mxw = fmaxf(mxw, sacc[mf][r]);
        }
    mxw = fmaxf(mxw, __shfl_xor(mxw, 16));
    mxw = fmaxf(mxw, __shfl_xor(mxw, 32));
    mxw = fmaxf(mxw, -1e30f);
    float sml = 0.f;
    #pragma unroll
    for (int mf = 0; mf < 5; ++mf)
        #pragma unroll
        for (int r = 0; r < 4; ++r) {
            const float p = expf(sacc[mf][r] - mxw);
            sacc[mf][r] = p;
            sml += p;
        }
    sml += __shfl_xor(sml, 16);
    sml += __shfl_xor(sml, 32);
    if (hi == 0) { redmax[wm][qq] = mxw; redsum[wm][qq] = sml; }
    __syncthreads();   // bar1

    #pragma unroll
    for (int l = 0; l < 10; ++l) {
        const int s = tid + 256 * l;
        const int r = s >> 4;
        const int c8 = s & 15;
        const int j = min(klo + r, SEQ - 1);
        const bf16x8 v = *(const bf16x8*)(qkv + base + (size_t)j * 768 + 2 * DMODEL + h * HDIM + c8 * 8);
        *(bf16x8*)&KV[(r * 128 + c8 * 8) ^ (((r >> 3) & 3) << 4)] = v;
    }

    {
        const float m0 = redmax[0][qq], m1 = redmax[1][qq];
        const float mx = fmaxf(m0, m1);
        const float tot = redsum[0][qq] * expf(m0 - mx) + redsum[1][qq] * expf(m1 - mx);
        const float fac = expf(mxw - mx) / tot;
        #pragma unroll
        for (int mf = 0; mf < 5; ++mf)
            #pragma unroll
            for (int r = 0; r < 4; ++r) {
                const int key = wm * 80 + mf * 16 + hi * 4 + r;
                QP[(qq * 160 + key) ^ ((qq & 3) << 3)] = f2bf(sacc[mf][r] * fac);
            }
    }
    __syncthreads();   // bar2

    f32x4 oacc[2][2];
    #pragma unroll
    for (int mf = 0; mf < 2; ++mf)
        #pragma unroll
        for (int nf = 0; nf < 2; ++nf) oacc[mf][nf] = (f32x4){0.f, 0.f, 0.f, 0.f};
    const int dimb = wid * 32;
    #pragma unroll
    for (int ksp = 0; ksp < 5; ++ksp) {
        bf16x8 vf0, vf1;
        #pragma unroll
        for (int j = 0; j < 8; ++j) {
            const int key = ksp * 32 + hi * 8 + j;
            const int x = ((key >> 3) & 3) << 4;
            vf0[j] = KV[(key * 128 + dimb + lo) ^ x];
            vf1[j] = KV[(key * 128 + dimb + 16 + lo) ^ x];
        }
        #pragma unroll
        for (int mf = 0; mf < 2; ++mf) {
            const int prow = mf * 16 + lo;
            const bf16x8 pf = *(const bf16x8*)&QP[(prow * 160 + ksp * 32 + hi * 8) ^ ((prow & 3) << 3)];
            oacc[mf][0] = __builtin_amdgcn_mfma_f32_16x16x32_bf16(pf, vf0, oacc[mf][0], 0, 0, 0);
            oacc[mf][1] = __builtin_amdgcn_mfma_f32_16x16x32_bf16(pf, vf1, oacc[mf][1], 0, 0, 0);
        }
    }
    #pragma unroll
    for (int mf = 0; mf < 2; ++mf)
        #pragma unroll
        for (int r = 0; r < 4; ++r) {
            const int q = mf * 16 + hi * 4 + r;
            if (i0 + q < SEQ) {
                short* dst = ctx + ((size_t)b * SEQ + i0 + q) * DMODEL + h * HDIM + dimb;
                dst[lo]      = f2bf(oacc[mf][0][r]);
                dst[16 + lo] = f2bf(oacc[mf][1][r]);
            }
        }
}

// ---------------------------------------------------------------------------
// Launch
// ---------------------------------------------------------------------------
extern "C" void kernel_launch(void* const* d_in, const int* in_sizes, int n_in,
                              void* d_out, int out_size, void* d_ws, size_t ws_size,
                              hipStream_t stream) {
    const float* src       = (const float*)d_in[0];
    const float* enc_w     = (const float*)d_in[1];
    const float* enc_b     = (const float*)d_in[2];
    const float* in_proj_w = (const float*)d_in[3];
    const float* in_proj_b = (const float*)d_in[4];
    const float* out_proj_w= (const float*)d_in[5];
    const float* out_proj_b= (const float*)d_in[6];
    const float* ln1_g     = (const float*)d_in[7];
    const float* ln1_b     = (const float*)d_in[8];
    const float* ff1_w     = (const float*)d_in[9];
    const float* ff1_b     = (const float*)d_in[10];
    const float* ff2_w     = (const float*)d_in[11];
    const float* ff2_b     = (const float*)d_in[12];
    const float* ln2_g     = (const float*)d_in[13];
    const float* ln2_b     = (const float*)d_in[14];
    const float* dec_w     = (const float*)d_in[15];
    const float* dec_b     = (const float*)d_in[16];
    const int*   nptr      = (const int*)d_in[17];

    // workspace layout (shorts for bf16 activations)
    short* SW   = (short*)d_ws;
    short* X    = SW;                   //  8,192,000 shorts (encode out; later X2)
    short* QKV  = SW + 8192000;         // 24,576,000 (later FFH)
    short* CTX  = SW + 32768000;        //  8,192,000 (then X1 in-place)
    float* PE   = (float*)(SW + 49152000);   // 512,000 floats
    short* WB   = SW + 50176000;        //   442,368 shorts (bf16 weights)
    float* QKVB = (float*)(SW + 50618368);   // 768 floats (scaled qkv bias)
    short* X1   = CTX;                  // LN1 output (in-place over CTX)
    short* FFH  = QKV;
    short* X2   = X;                    // LN2 output (over X, free after LN1)
    float* OUT  = (float*)d_out;

    short* enc_wb  = WB;
    short* inp_wb  = WB + 32768;
    short* outp_wb = WB + 229376;
    short* ff1_wb  = WB + 294912;
    short* ff2_wb  = WB + 360448;
    short* dec_wb  = WB + 425984;

    pe_kernel<<<SEQ, 256, 0, stream>>>(PE);
    wconv_kernel<<<1728, 256, 0, stream>>>(enc_w, in_proj_w, out_proj_w,
                                           ff1_w, ff2_w, dec_w, WB);
    qkvbias_kernel<<<3, 256, 0, stream>>>(in_proj_b, QKVB);

    // encode: fp32 src -> bf16 X (+bias+pe)
    gemm_mfma_kernel<2, false, true><<<dim3(MROWS / 128, DMODEL / 64), 256, 0, stream>>>(
        src, enc_wb, enc_b, PE, X, MROWS, DMODEL, INSZ);
    // qkv
    gemm_mfma_kernel<0, true, true><<<dim3(MROWS / 128, (3 * DMODEL) / 64), 256, 0, stream>>>(
        X, inp_wb, QKVB, nullptr, QKV, MROWS, 3 * DMODEL, DMODEL);
    // attention
    attn_mfma_kernel<<<BATCH * NHEAD * NQT, 256, 0, stream>>>(QKV, CTX, nptr);
    // out_proj + residual(X) + LN1 -> X1 (in-place over CTX)
    gemm_ln_kernel<<<MROWS / 64, 256, 0, stream>>>(
        CTX, outp_wb, out_proj_b, X, ln1_g, ln1_b, X1, MROWS, DMODEL);
    // ff1 (relu)
    gemm_mfma_kernel<1, true, true><<<dim3(MROWS / 128, FFDIM / 64), 256, 0, stream>>>(
        X1, ff1_wb, ff1_b, nullptr, FFH, MROWS, FFDIM, DMODEL);
    // ff2 + residual(X1) + LN2 -> X2 (over X)
    gemm_ln_kernel<<<MROWS / 64, 256, 0, stream>>>(
        FFH, ff2_wb, ff2_b, X1, ln2_g, ln2_b, X2, MROWS, FFDIM);
    // decode -> fp32 out
    gemm_mfma_kernel<0, true, false><<<dim3(MROWS / 128, OUTSZ / 64), 256, 0, stream>>>(
        X2, dec_wb, dec_b, nullptr, OUT, MROWS, OUTSZ, DMODEL);
}

// Round 12
// 210.158 us; speedup vs baseline: 5.0938x; 1.1297x over previous
//
#include <hip/hip_runtime.h>
#include <hip/hip_bf16.h>
#include <math.h>

// Problem constants (fixed by the reference)
#define BATCH 16
#define SEQ   2000
#define INSZ  128
#define DMODEL 256
#define NHEAD 2
#define HDIM  128
#define FFDIM 256
#define OUTSZ 64
#define MROWS (BATCH * SEQ)   // 32000

// Attention tiling
#define TQ 32
#define TK 160
#define NQT ((SEQ + TQ - 1) / TQ)   // 63

typedef __attribute__((ext_vector_type(8))) short bf16x8;
typedef __attribute__((ext_vector_type(4))) float f32x4;

static __device__ __forceinline__ short f2bf(float f) {
    union { float f; unsigned int u; } c; c.f = f;
    unsigned int u = c.u + 0x7FFF + ((c.u >> 16) & 1);   // round-to-nearest-even
    return (short)(u >> 16);
}
static __device__ __forceinline__ float bf2f(short s) {
    union { unsigned int u; float f; } c; c.u = ((unsigned int)(unsigned short)s) << 16;
    return c.f;
}

// Bijective XCD swizzle (m204): hardware XCD = blockIdx%8; give each XCD a
// CONTIGUOUS chunk of the logical work order so neighbor work shares its L2.
static __device__ __forceinline__ int xcd_swizzle(int bid, int nwg) {
    const int q = nwg >> 3, r = nwg & 7;
    const int xcd = bid & 7, pos = bid >> 3;
    return (xcd < r ? xcd * (q + 1) : r * (q + 1) + (xcd - r) * q) + pos;
}

// ---------------------------------------------------------------------------
// Merged setup: PE table (blocks 0..1999), weight conversion (next 1728),
// qkv bias pre-scale (last 3). One launch instead of three.
// in_proj Q-rows pre-scaled by 1/sqrt(128).
// ---------------------------------------------------------------------------
__global__ __launch_bounds__(256) void setup_kernel(const float* __restrict__ w0,
                                                    const float* __restrict__ w1,
                                                    const float* __restrict__ w2,
                                                    const float* __restrict__ w3,
                                                    const float* __restrict__ w4,
                                                    const float* __restrict__ w5,
                                                    const float* __restrict__ inb,
                                                    float* __restrict__ pe,
                                                    short* __restrict__ wdst,
                                                    float* __restrict__ bdst) {
    const int blk = blockIdx.x;
    const int t = threadIdx.x;
    if (blk < SEQ) {
        const double c = -9.210340371976184 / 256.0;  // -ln(10000)/D
        const double div = exp((double)(t & ~1) * c);
        const double ang = (double)blk * div;
        pe[(size_t)blk * DMODEL + t] = (float)((t & 1) ? cos(ang) : sin(ang));
    } else if (blk < SEQ + 1728) {
        const int idx = (blk - SEQ) * 256 + t;
        float v;
        if (idx < 32768) v = w0[idx];
        else if (idx < 229376) {
            const int e = idx - 32768;
            v = w1[e];
            if (e < 65536) v *= 0.08838834764831845f;   // Q rows
        }
        else if (idx < 294912) v = w2[idx - 229376];
        else if (idx < 360448) v = w3[idx - 294912];
        else if (idx < 425984) v = w4[idx - 360448];
        else                   v = w5[idx - 425984];
        wdst[idx] = f2bf(v);
    } else {
        const int i = (blk - SEQ - 1728) * 256 + t;   // 0..767
        bdst[i] = inb[i] * (i < 256 ? 0.08838834764831845f : 1.f);
    }
}

// ---------------------------------------------------------------------------
// bf16 MFMA GEMM: C[M,N] = A[M,K] @ W[N,K]^T + bias[N]  (+ epilogue)
// 1-D grid, XCD-swizzled, n-fastest: blocks sharing an A-panel are
// consecutive work ids -> same XCD L2. nbx = N/64.
// ABF: A already bf16. OBF: write bf16. EPI: 0=bias, 1=+relu, 2=+pe.
// ---------------------------------------------------------------------------
template <int EPI, bool ABF, bool OBF>
__global__ __launch_bounds__(256) void gemm_mfma_kernel(const void* __restrict__ Av,
                                                        const short* __restrict__ W,
                                                        const float* __restrict__ bias,
                                                        const float* __restrict__ pe,
                                                        void* __restrict__ Cv,
                                                        int M, int N, int K, int nbx) {
    __shared__ short As[128][72];
    __shared__ short Ws[64][72];

    const int bid = xcd_swizzle(blockIdx.x, gridDim.x);
    const int m0 = (bid / nbx) * 128;
    const int n0 = (bid % nbx) * 64;
    const int tid = threadIdx.x;
    const int wid = tid >> 6;
    const int wr = wid >> 1;
    const int wc = wid & 1;
    const int lane = tid & 63;
    const int lo = lane & 15;
    const int hi = lane >> 4;

    f32x4 acc[4][2];
    #pragma unroll
    for (int mt = 0; mt < 4; ++mt)
        #pragma unroll
        for (int nt = 0; nt < 2; ++nt) acc[mt][nt] = (f32x4){0.f, 0.f, 0.f, 0.f};

    for (int k0 = 0; k0 < K; k0 += 64) {
        if (ABF) {
            const short* A = (const short*)Av;
            #pragma unroll
            for (int l = 0; l < 4; ++l) {
                const int s = tid + 256 * l;
                const int r = s >> 3;
                const int c8 = s & 7;
                const bf16x8 v = *(const bf16x8*)(A + (size_t)(m0 + r) * K + k0 + c8 * 8);
                *(bf16x8*)&As[r][c8 * 8] = v;
            }
        } else {
            const float* A = (const float*)Av;
            #pragma unroll
            for (int l = 0; l < 8; ++l) {
                const int s = tid + 256 * l;
                const int r = s >> 4;
                const int c4 = s & 15;
                const float4 v = *(const float4*)(A + (size_t)(m0 + r) * K + k0 + c4 * 4);
                *(short4*)&As[r][c4 * 4] = make_short4(f2bf(v.x), f2bf(v.y), f2bf(v.z), f2bf(v.w));
            }
        }
        #pragma unroll
        for (int l = 0; l < 2; ++l) {
            const int s = tid + 256 * l;
            const int r = s >> 3;
            const int c8 = s & 7;
            const bf16x8 v = *(const bf16x8*)(W + (size_t)(n0 + r) * K + k0 + c8 * 8);
            *(bf16x8*)&Ws[r][c8 * 8] = v;
        }
        __syncthreads();

        #pragma unroll
        for (int kk = 0; kk < 2; ++kk) {
            bf16x8 bfr[2];
            #pragma unroll
            for (int nt = 0; nt < 2; ++nt)
                bfr[nt] = *(const bf16x8*)&Ws[wc * 32 + nt * 16 + lo][kk * 32 + hi * 8];
            #pragma unroll
            for (int mt = 0; mt < 4; ++mt) {
                const bf16x8 afr = *(const bf16x8*)&As[wr * 64 + mt * 16 + lo][kk * 32 + hi * 8];
                acc[mt][0] = __builtin_amdgcn_mfma_f32_16x16x32_bf16(afr, bfr[0], acc[mt][0], 0, 0, 0);
                acc[mt][1] = __builtin_amdgcn_mfma_f32_16x16x32_bf16(afr, bfr[1], acc[mt][1], 0, 0, 0);
            }
        }
        __syncthreads();
    }

    // epilogue: C/D frag mapping col=lane&15, row=(lane>>4)*4+reg  [m89]
    #pragma unroll
    for (int nt = 0; nt < 2; ++nt) {
        const int col = n0 + wc * 32 + nt * 16 + lo;
        const float bi = bias[col];
        #pragma unroll
        for (int mt = 0; mt < 4; ++mt) {
            #pragma unroll
            for (int r = 0; r < 4; ++r) {
                const int row = m0 + wr * 64 + mt * 16 + hi * 4 + r;
                float v = acc[mt][nt][r] + bi;
                if (EPI == 1) v = fmaxf(v, 0.f);
                if (EPI == 2) v += pe[(size_t)(row % SEQ) * DMODEL + col];
                if (OBF) ((short*)Cv)[(size_t)row * N + col] = f2bf(v);
                else     ((float*)Cv)[(size_t)row * N + col] = v;
            }
        }
    }
}

// ---------------------------------------------------------------------------
// Fused GEMM + bias + residual-add + LayerNorm (N=256 fixed), unchanged
// from round 11 (measured good). 1-D row grid; W is L2-resident -> no swizzle.
// ---------------------------------------------------------------------------
__global__ __launch_bounds__(256) void gemm_ln_kernel(const short* __restrict__ A,
                                                      const short* __restrict__ W,
                                                      const float* __restrict__ bias,
                                                      const short* __restrict__ R,
                                                      const float* __restrict__ g,
                                                      const float* __restrict__ beta,
                                                      short* __restrict__ out,
                                                      int M, int K) {
    __shared__ short As[64][72];
    __shared__ short Ws[256][72];
    __shared__ float rsum[64][2];
    __shared__ float rsq[64][2];

    const int tid = threadIdx.x;
    const int m0 = blockIdx.x * 64;
    const int wid = tid >> 6;
    const int wr = wid >> 1;
    const int wc = wid & 1;
    const int lane = tid & 63;
    const int lo = lane & 15;
    const int hi = lane >> 4;

    f32x4 acc[2][8];
    #pragma unroll
    for (int mt = 0; mt < 2; ++mt)
        #pragma unroll
        for (int nt = 0; nt < 8; ++nt) acc[mt][nt] = (f32x4){0.f, 0.f, 0.f, 0.f};

    for (int k0 = 0; k0 < K; k0 += 64) {
        #pragma unroll
        for (int l = 0; l < 2; ++l) {
            const int s = tid + 256 * l;
            const int r = s >> 3;
            const int c8 = s & 7;
            *(bf16x8*)&As[r][c8 * 8] = *(const bf16x8*)(A + (size_t)(m0 + r) * K + k0 + c8 * 8);
        }
        #pragma unroll
        for (int l = 0; l < 8; ++l) {
            const int s = tid + 256 * l;
            const int r = s >> 3;
            const int c8 = s & 7;
            *(bf16x8*)&Ws[r][c8 * 8] = *(const bf16x8*)(W + (size_t)r * K + k0 + c8 * 8);
        }
        __syncthreads();

        #pragma unroll
        for (int kk = 0; kk < 2; ++kk) {
            bf16x8 bfr[8];
            #pragma unroll
            for (int nt = 0; nt < 8; ++nt)
                bfr[nt] = *(const bf16x8*)&Ws[wc * 128 + nt * 16 + lo][kk * 32 + hi * 8];
            #pragma unroll
            for (int mt = 0; mt < 2; ++mt) {
                const bf16x8 afr = *(const bf16x8*)&As[wr * 32 + mt * 16 + lo][kk * 32 + hi * 8];
                #pragma unroll
                for (int nt = 0; nt < 8; ++nt)
                    acc[mt][nt] = __builtin_amdgcn_mfma_f32_16x16x32_bf16(afr, bfr[nt], acc[mt][nt], 0, 0, 0);
            }
        }
        __syncthreads();
    }

    float bi[8], gg[8], bb[8];
    #pragma unroll
    for (int nt = 0; nt < 8; ++nt) {
        const int col = wc * 128 + nt * 16 + lo;
        bi[nt] = bias[col]; gg[nt] = g[col]; bb[nt] = beta[col];
    }

    #pragma unroll
    for (int mt = 0; mt < 2; ++mt) {
        #pragma unroll
        for (int r = 0; r < 4; ++r) {
            const int rl = wr * 32 + mt * 16 + hi * 4 + r;
            const size_t grow = (size_t)(m0 + rl) * DMODEL;
            float s = 0.f, q = 0.f;
            #pragma unroll
            for (int nt = 0; nt < 8; ++nt) {
                const int col = wc * 128 + nt * 16 + lo;
                float v = acc[mt][nt][r] + bi[nt] + bf2f(R[grow + col]);
                acc[mt][nt][r] = v;
                s += v; q += v * v;
            }
            #pragma unroll
            for (int o = 1; o < 16; o <<= 1) { s += __shfl_xor(s, o); q += __shfl_xor(q, o); }
            if (lo == 0) { rsum[rl][wc] = s; rsq[rl][wc] = q; }
        }
    }
    __syncthreads();

    #pragma unroll
    for (int mt = 0; mt < 2; ++mt) {
        #pragma unroll
        for (int r = 0; r < 4; ++r) {
            const int rl = wr * 32 + mt * 16 + hi * 4 + r;
            const float mean = (rsum[rl][0] + rsum[rl][1]) * (1.f / DMODEL);
            const float var = (rsq[rl][0] + rsq[rl][1]) * (1.f / DMODEL) - mean * mean;
            const float rstd = rsqrtf(var + 1e-5f);
            const size_t grow = (size_t)(m0 + rl) * DMODEL;
            #pragma unroll
            for (int nt = 0; nt < 8; ++nt) {
                const int col = wc * 128 + nt * 16 + lo;
                out[grow + col] = f2bf((acc[mt][nt][r] - mean) * rstd * gg[nt] + bb[nt]);
            }
        }
    }
}

// ---------------------------------------------------------------------------
// MFMA banded attention, bf16 I/O. Round-10 structure + XCD swizzle so the
// ~5 consecutive tiles sharing band K/V rows land on the same XCD's L2.
// ---------------------------------------------------------------------------
__global__ __launch_bounds__(256, 3) void attn_mfma_kernel(const short* __restrict__ qkv,
                                                           short* __restrict__ ctx,
                                                           const int* __restrict__ nptr) {
    __shared__ short KV[160 * 128];
    __shared__ short QP[32 * 160];
    __shared__ float redmax[2][32];
    __shared__ float redsum[2][32];

    const int tid = threadIdx.x;
    const int bid = xcd_swizzle(blockIdx.x, gridDim.x);
    const int tile = bid % NQT;
    const int bh = bid / NQT;
    const int h = bh & (NHEAD - 1);
    const int b = bh >> 1;
    const int NN = *nptr;               // 100
    const int i0 = tile * TQ;
    const int klo = max(0, i0 - NN);
    const size_t base = (size_t)b * SEQ * 768;

    const int lane = tid & 63;
    const int wid = tid >> 6;
    const int lo = lane & 15;
    const int hi = lane >> 4;
    const int wm = wid >> 1;
    const int wn = wid & 1;

    #pragma unroll
    for (int l = 0; l < 10; ++l) {
        const int s = tid + 256 * l;
        const int r = s >> 4;
        const int c8 = s & 15;
        const int j = min(klo + r, SEQ - 1);
        const bf16x8 v = *(const bf16x8*)(qkv + base + (size_t)j * 768 + DMODEL + h * HDIM + c8 * 8);
        *(bf16x8*)&KV[(r * 128 + c8 * 8) ^ ((r & 7) << 3)] = v;
    }
    #pragma unroll
    for (int l = 0; l < 2; ++l) {
        const int s = tid + 256 * l;
        const int r = s >> 4;
        const int c8 = s & 15;
        const int qi = min(i0 + r, SEQ - 1);
        const bf16x8 v = *(const bf16x8*)(qkv + base + (size_t)qi * 768 + h * HDIM + c8 * 8);
        *(bf16x8*)&QP[(r * 128 + c8 * 8) ^ ((r & 7) << 3)] = v;
    }
    __syncthreads();   // bar0

    f32x4 sacc[5];
    #pragma unroll
    for (int mf = 0; mf < 5; ++mf) sacc[mf] = (f32x4){0.f, 0.f, 0.f, 0.f};
    #pragma unroll
    for (int ks = 0; ks < 4; ++ks) {
        const int qrow = wn * 16 + lo;
        const bf16x8 qf = *(const bf16x8*)&QP[(qrow * 128 + ks * 32 + hi * 8) ^ ((qrow & 7) << 3)];
        #pragma unroll
        for (int mf = 0; mf < 5; ++mf) {
            const int krow = wm * 80 + mf * 16 + lo;
            const bf16x8 kf = *(const bf16x8*)&KV[(krow * 128 + ks * 32 + hi * 8) ^ ((krow & 7) << 3)];
            sacc[mf] = __builtin_amdgcn_mfma_f32_16x16x32_bf16(kf, qf, sacc[mf], 0, 0, 0);
        }
    }

    const int qq = wn * 16 + lo;
    const int qi = i0 + qq;
    float mxw = -3.4e38f;
    #pragma unroll
    for (int mf = 0; mf < 5; ++mf)
        #pragma unroll
        for (int r = 0; r < 4; ++r) {
            const int ja = klo + wm * 80 + mf * 16 + hi * 4 + r;
            const bool ok = (ja >= qi - NN) && (ja <= qi);
            sacc[mf][r] = ok ? sacc[mf][r] : -3.4e38f;
            mxw = fmaxf(mxw, sacc[mf][r]);
        }
    mxw = fmaxf(mxw, __shfl_xor(mxw, 16));
    mxw = fmaxf(mxw, __shfl_xor(mxw, 32));
    mxw = fmaxf(mxw, -1e30f);
    float sml = 0.f;
    #pragma unroll
    for (int mf = 0; mf < 5; ++mf)
        #pragma unroll
        for (int r = 0; r < 4; ++r) {
            const float p = expf(sacc[mf][r] - mxw);
            sacc[mf][r] = p;
            sml += p;
        }
    sml += __shfl_xor(sml, 16);
    sml += __shfl_xor(sml, 32);
    if (hi == 0) { redmax[wm][qq] = mxw; redsum[wm][qq] = sml; }
    __syncthreads();   // bar1

    #pragma unroll
    for (int l = 0; l < 10; ++l) {
        const int s = tid + 256 * l;
        const int r = s >> 4;
        const int c8 = s & 15;
        const int j = min(klo + r, SEQ - 1);
        const bf16x8 v = *(const bf16x8*)(qkv + base + (size_t)j * 768 + 2 * DMODEL + h * HDIM + c8 * 8);
        *(bf16x8*)&KV[(r * 128 + c8 * 8) ^ (((r >> 3) & 3) << 4)] = v;
    }

    {
        const float m0 = redmax[0][qq], m1 = redmax[1][qq];
        const float mx = fmaxf(m0, m1);
        const float tot = redsum[0][qq] * expf(m0 - mx) + redsum[1][qq] * expf(m1 - mx);
        const float fac = expf(mxw - mx) / tot;
        #pragma unroll
        for (int mf = 0; mf < 5; ++mf)
            #pragma unroll
            for (int r = 0; r < 4; ++r) {
                const int key = wm * 80 + mf * 16 + hi * 4 + r;
                QP[(qq * 160 + key) ^ ((qq & 3) << 3)] = f2bf(sacc[mf][r] * fac);
            }
    }
    __syncthreads();   // bar2

    f32x4 oacc[2][2];
    #pragma unroll
    for (int mf = 0; mf < 2; ++mf)
        #pragma unroll
        for (int nf = 0; nf < 2; ++nf) oacc[mf][nf] = (f32x4){0.f, 0.f, 0.f, 0.f};
    const int dimb = wid * 32;
    #pragma unroll
    for (int ksp = 0; ksp < 5; ++ksp) {
        bf16x8 vf0, vf1;
        #pragma unroll
        for (int j = 0; j < 8; ++j) {
            const int key = ksp * 32 + hi * 8 + j;
            const int x = ((key >> 3) & 3) << 4;
            vf0[j] = KV[(key * 128 + dimb + lo) ^ x];
            vf1[j] = KV[(key * 128 + dimb + 16 + lo) ^ x];
        }
        #pragma unroll
        for (int mf = 0; mf < 2; ++mf) {
            const int prow = mf * 16 + lo;
            const bf16x8 pf = *(const bf16x8*)&QP[(prow * 160 + ksp * 32 + hi * 8) ^ ((prow & 3) << 3)];
            oacc[mf][0] = __builtin_amdgcn_mfma_f32_16x16x32_bf16(pf, vf0, oacc[mf][0], 0, 0, 0);
            oacc[mf][1] = __builtin_amdgcn_mfma_f32_16x16x32_bf16(pf, vf1, oacc[mf][1], 0, 0, 0);
        }
    }
    #pragma unroll
    for (int mf = 0; mf < 2; ++mf)
        #pragma unroll
        for (int r = 0; r < 4; ++r) {
            const int q = mf * 16 + hi * 4 + r;
            if (i0 + q < SEQ) {
                short* dst = ctx + ((size_t)b * SEQ + i0 + q) * DMODEL + h * HDIM + dimb;
                dst[lo]      = f2bf(oacc[mf][0][r]);
                dst[16 + lo] = f2bf(oacc[mf][1][r]);
            }
        }
}

// ---------------------------------------------------------------------------
// Launch
// ---------------------------------------------------------------------------
extern "C" void kernel_launch(void* const* d_in, const int* in_sizes, int n_in,
                              void* d_out, int out_size, void* d_ws, size_t ws_size,
                              hipStream_t stream) {
    const float* src       = (const float*)d_in[0];
    const float* enc_w     = (const float*)d_in[1];
    const float* enc_b     = (const float*)d_in[2];
    const float* in_proj_w = (const float*)d_in[3];
    const float* in_proj_b = (const float*)d_in[4];
    const float* out_proj_w= (const float*)d_in[5];
    const float* out_proj_b= (const float*)d_in[6];
    const float* ln1_g     = (const float*)d_in[7];
    const float* ln1_b     = (const float*)d_in[8];
    const float* ff1_w     = (const float*)d_in[9];
    const float* ff1_b     = (const float*)d_in[10];
    const float* ff2_w     = (const float*)d_in[11];
    const float* ff2_b     = (const float*)d_in[12];
    const float* ln2_g     = (const float*)d_in[13];
    const float* ln2_b     = (const float*)d_in[14];
    const float* dec_w     = (const float*)d_in[15];
    const float* dec_b     = (const float*)d_in[16];
    const int*   nptr      = (const int*)d_in[17];

    // workspace layout (shorts for bf16 activations)
    short* SW   = (short*)d_ws;
    short* X    = SW;                   //  8,192,000 shorts (encode out; later X2)
    short* QKV  = SW + 8192000;         // 24,576,000 (later FFH)
    short* CTX  = SW + 32768000;        //  8,192,000 (then X1 in-place)
    float* PE   = (float*)(SW + 49152000);   // 512,000 floats
    short* WB   = SW + 50176000;        //   442,368 shorts (bf16 weights)
    float* QKVB = (float*)(SW + 50618368);   // 768 floats (scaled qkv bias)
    short* X1   = CTX;                  // LN1 output (in-place over CTX)
    short* FFH  = QKV;
    short* X2   = X;                    // LN2 output (over X, free after LN1)
    float* OUT  = (float*)d_out;

    short* enc_wb  = WB;
    short* inp_wb  = WB + 32768;
    short* outp_wb = WB + 229376;
    short* ff1_wb  = WB + 294912;
    short* ff2_wb  = WB + 360448;
    short* dec_wb  = WB + 425984;

    // merged setup: PE (2000) + wconv (1728) + qkv bias (3)
    setup_kernel<<<SEQ + 1728 + 3, 256, 0, stream>>>(
        enc_w, in_proj_w, out_proj_w, ff1_w, ff2_w, dec_w, in_proj_b,
        PE, WB, QKVB);

    // encode: fp32 src -> bf16 X (+bias+pe); grid 250*4
    gemm_mfma_kernel<2, false, true><<<(MROWS / 128) * (DMODEL / 64), 256, 0, stream>>>(
        src, enc_wb, enc_b, PE, X, MROWS, DMODEL, INSZ, DMODEL / 64);
    // qkv; grid 250*12
    gemm_mfma_kernel<0, true, true><<<(MROWS / 128) * ((3 * DMODEL) / 64), 256, 0, stream>>>(
        X, inp_wb, QKVB, nullptr, QKV, MROWS, 3 * DMODEL, DMODEL, (3 * DMODEL) / 64);
    // attention; grid 2016
    attn_mfma_kernel<<<BATCH * NHEAD * NQT, 256, 0, stream>>>(QKV, CTX, nptr);
    // out_proj + residual(X) + LN1 -> X1 (in-place over CTX)
    gemm_ln_kernel<<<MROWS / 64, 256, 0, stream>>>(
        CTX, outp_wb, out_proj_b, X, ln1_g, ln1_b, X1, MROWS, DMODEL);
    // ff1 (relu); grid 250*4
    gemm_mfma_kernel<1, true, true><<<(MROWS / 128) * (FFDIM / 64), 256, 0, stream>>>(
        X1, ff1_wb, ff1_b, nullptr, FFH, MROWS, FFDIM, DMODEL, FFDIM / 64);
    // ff2 + residual(X1) + LN2 -> X2 (over X)
    gemm_ln_kernel<<<MROWS / 64, 256, 0, stream>>>(
        FFH, ff2_wb, ff2_b, X1, ln2_g, ln2_b, X2, MROWS, FFDIM);
    // decode -> fp32 out; grid 250*1
    gemm_mfma_kernel<0, true, false><<<(MROWS / 128) * (OUTSZ / 64), 256, 0, stream>>>(
        X2, dec_wb, dec_b, nullptr, OUT, MROWS, OUTSZ, DMODEL, OUTSZ / 64);
}

// Round 13
// 202.546 us; speedup vs baseline: 5.2852x; 1.0376x over previous
//
#include <hip/hip_runtime.h>
#include <hip/hip_bf16.h>
#include <math.h>

// Problem constants (fixed by the reference)
#define BATCH 16
#define SEQ   2000
#define INSZ  128
#define DMODEL 256
#define NHEAD 2
#define HDIM  128
#define FFDIM 256
#define OUTSZ 64
#define MROWS (BATCH * SEQ)   // 32000

// Attention tiling
#define TQ 32
#define TK 160
#define NQT ((SEQ + TQ - 1) / TQ)   // 63

typedef __attribute__((ext_vector_type(8))) short bf16x8;
typedef __attribute__((ext_vector_type(4))) float f32x4;

static __device__ __forceinline__ short f2bf(float f) {
    union { float f; unsigned int u; } c; c.f = f;
    unsigned int u = c.u + 0x7FFF + ((c.u >> 16) & 1);   // round-to-nearest-even
    return (short)(u >> 16);
}
static __device__ __forceinline__ float bf2f(short s) {
    union { unsigned int u; float f; } c; c.u = ((unsigned int)(unsigned short)s) << 16;
    return c.f;
}

// Bijective XCD swizzle (m204)
static __device__ __forceinline__ int xcd_swizzle(int bid, int nwg) {
    const int q = nwg >> 3, r = nwg & 7;
    const int xcd = bid & 7, pos = bid >> 3;
    return (xcd < r ? xcd * (q + 1) : r * (q + 1) + (xcd - r) * q) + pos;
}

// ---------------------------------------------------------------------------
// Merged setup: PE (2000 blocks) + weight conversion (1728) + qkv bias (3).
// in_proj Q-rows pre-scaled by 1/sqrt(128).
// ---------------------------------------------------------------------------
__global__ __launch_bounds__(256) void setup_kernel(const float* __restrict__ w0,
                                                    const float* __restrict__ w1,
                                                    const float* __restrict__ w2,
                                                    const float* __restrict__ w3,
                                                    const float* __restrict__ w4,
                                                    const float* __restrict__ w5,
                                                    const float* __restrict__ inb,
                                                    float* __restrict__ pe,
                                                    short* __restrict__ wdst,
                                                    float* __restrict__ bdst) {
    const int blk = blockIdx.x;
    const int t = threadIdx.x;
    if (blk < SEQ) {
        const double c = -9.210340371976184 / 256.0;  // -ln(10000)/D
        const double div = exp((double)(t & ~1) * c);
        const double ang = (double)blk * div;
        pe[(size_t)blk * DMODEL + t] = (float)((t & 1) ? cos(ang) : sin(ang));
    } else if (blk < SEQ + 1728) {
        const int idx = (blk - SEQ) * 256 + t;
        float v;
        if (idx < 32768) v = w0[idx];
        else if (idx < 229376) {
            const int e = idx - 32768;
            v = w1[e];
            if (e < 65536) v *= 0.08838834764831845f;   // Q rows
        }
        else if (idx < 294912) v = w2[idx - 229376];
        else if (idx < 360448) v = w3[idx - 294912];
        else if (idx < 425984) v = w4[idx - 360448];
        else                   v = w5[idx - 425984];
        wdst[idx] = f2bf(v);
    } else {
        const int i = (blk - SEQ - 1728) * 256 + t;
        bdst[i] = inb[i] * (i < 256 ? 0.08838834764831845f : 1.f);
    }
}

// ---------------------------------------------------------------------------
// bf16 MFMA GEMM (encode / qkv). 1-D grid, XCD-swizzled, n-fastest.
// ABF: A bf16. EPI: 0=bias, 2=bias+pe. Output bf16.
// ---------------------------------------------------------------------------
template <int EPI, bool ABF>
__global__ __launch_bounds__(256) void gemm_mfma_kernel(const void* __restrict__ Av,
                                                        const short* __restrict__ W,
                                                        const float* __restrict__ bias,
                                                        const float* __restrict__ pe,
                                                        short* __restrict__ C,
                                                        int M, int N, int K, int nbx) {
    __shared__ short As[128][72];
    __shared__ short Ws[64][72];

    const int bid = xcd_swizzle(blockIdx.x, gridDim.x);
    const int m0 = (bid / nbx) * 128;
    const int n0 = (bid % nbx) * 64;
    const int tid = threadIdx.x;
    const int wid = tid >> 6;
    const int wr = wid >> 1;
    const int wc = wid & 1;
    const int lane = tid & 63;
    const int lo = lane & 15;
    const int hi = lane >> 4;

    f32x4 acc[4][2];
    #pragma unroll
    for (int mt = 0; mt < 4; ++mt)
        #pragma unroll
        for (int nt = 0; nt < 2; ++nt) acc[mt][nt] = (f32x4){0.f, 0.f, 0.f, 0.f};

    for (int k0 = 0; k0 < K; k0 += 64) {
        if (ABF) {
            const short* A = (const short*)Av;
            #pragma unroll
            for (int l = 0; l < 4; ++l) {
                const int s = tid + 256 * l;
                const int r = s >> 3;
                const int c8 = s & 7;
                *(bf16x8*)&As[r][c8 * 8] = *(const bf16x8*)(A + (size_t)(m0 + r) * K + k0 + c8 * 8);
            }
        } else {
            const float* A = (const float*)Av;
            #pragma unroll
            for (int l = 0; l < 8; ++l) {
                const int s = tid + 256 * l;
                const int r = s >> 4;
                const int c4 = s & 15;
                const float4 v = *(const float4*)(A + (size_t)(m0 + r) * K + k0 + c4 * 4);
                *(short4*)&As[r][c4 * 4] = make_short4(f2bf(v.x), f2bf(v.y), f2bf(v.z), f2bf(v.w));
            }
        }
        #pragma unroll
        for (int l = 0; l < 2; ++l) {
            const int s = tid + 256 * l;
            const int r = s >> 3;
            const int c8 = s & 7;
            *(bf16x8*)&Ws[r][c8 * 8] = *(const bf16x8*)(W + (size_t)(n0 + r) * K + k0 + c8 * 8);
        }
        __syncthreads();

        #pragma unroll
        for (int kk = 0; kk < 2; ++kk) {
            bf16x8 bfr[2];
            #pragma unroll
            for (int nt = 0; nt < 2; ++nt)
                bfr[nt] = *(const bf16x8*)&Ws[wc * 32 + nt * 16 + lo][kk * 32 + hi * 8];
            #pragma unroll
            for (int mt = 0; mt < 4; ++mt) {
                const bf16x8 afr = *(const bf16x8*)&As[wr * 64 + mt * 16 + lo][kk * 32 + hi * 8];
                acc[mt][0] = __builtin_amdgcn_mfma_f32_16x16x32_bf16(afr, bfr[0], acc[mt][0], 0, 0, 0);
                acc[mt][1] = __builtin_amdgcn_mfma_f32_16x16x32_bf16(afr, bfr[1], acc[mt][1], 0, 0, 0);
            }
        }
        __syncthreads();
    }

    #pragma unroll
    for (int nt = 0; nt < 2; ++nt) {
        const int col = n0 + wc * 32 + nt * 16 + lo;
        const float bi = bias[col];
        #pragma unroll
        for (int mt = 0; mt < 4; ++mt) {
            #pragma unroll
            for (int r = 0; r < 4; ++r) {
                const int row = m0 + wr * 64 + mt * 16 + hi * 4 + r;
                float v = acc[mt][nt][r] + bi;
                if (EPI == 2) v += pe[(size_t)(row % SEQ) * DMODEL + col];
                C[(size_t)row * N + col] = f2bf(v);
            }
        }
    }
}

// ---------------------------------------------------------------------------
// Fused tail: out_proj + X-residual + LN1 -> ff1(+relu) -> ff2 + X1-residual
// + LN2 -> dec, one 32-row block, everything after CTX/X in LDS.
// 256 thr = 4 waves (2 row-halves x 2 col-halves). LDS 72.5 KB -> 2 blk/CU.
// Numerics identical to the unfused chain (bf16 rounding at same points).
// ---------------------------------------------------------------------------
__global__ __launch_bounds__(256) void tail_fused_kernel(const short* __restrict__ CTX,
                                                         const short* __restrict__ X,
                                                         const short* __restrict__ Wo,
                                                         const float* __restrict__ bo,
                                                         const float* __restrict__ g1,
                                                         const float* __restrict__ be1,
                                                         const short* __restrict__ W1,
                                                         const float* __restrict__ bF1,
                                                         const short* __restrict__ W2,
                                                         const float* __restrict__ bF2,
                                                         const float* __restrict__ g2,
                                                         const float* __restrict__ be2,
                                                         const short* __restrict__ Wd,
                                                         const float* __restrict__ bd,
                                                         float* __restrict__ out) {
    __shared__ short Ws[256][72];        // weight K-tile staging (reused all stages)
    __shared__ short Abuf[4][32][72];    // CTX (S1), then FFH (S2 out / S3 in)
    __shared__ short Xbuf[4][32][72];    // X1 (S1 out), then X2 (S3 out / S4 in)
    __shared__ float rsum[32][2];
    __shared__ float rsq[32][2];

    const int tid = threadIdx.x;
    const int m0 = blockIdx.x * 32;
    const int wid = tid >> 6;
    const int wr = wid >> 1;            // row half: rows [wr*16, +16)
    const int wc = wid & 1;             // col half: cols [wc*128, +128)
    const int lane = tid & 63;
    const int lo = lane & 15;
    const int hi = lane >> 4;

    // ---- load CTX rows into Abuf (chunked: chunk c = k in [64c,64c+64)) ----
    #pragma unroll
    for (int l = 0; l < 4; ++l) {
        const int s = tid + 256 * l;
        const int r = s >> 5;           // 0..31
        const int c8 = s & 31;          // 0..31 (8-elem groups over k=0..255)
        *(bf16x8*)&Abuf[c8 >> 3][r][(c8 & 7) * 8] =
            *(const bf16x8*)(CTX + (size_t)(m0 + r) * DMODEL + c8 * 8);
    }
    __syncthreads();

    f32x4 acc[8];

    // K=256 GEMM from LDS buf against global weight WG, acc[8] frags
    #define STAGE_K256(BUF, WG)                                                          \
    {                                                                                    \
        _Pragma("unroll") for (int nt = 0; nt < 8; ++nt) acc[nt] = (f32x4){0,0,0,0};     \
        for (int kt = 0; kt < 4; ++kt) {                                                 \
            _Pragma("unroll") for (int l = 0; l < 8; ++l) {                              \
                const int s = tid + 256 * l;                                             \
                const int rr = s >> 3, c8 = s & 7;                                       \
                *(bf16x8*)&Ws[rr][c8 * 8] =                                              \
                    *(const bf16x8*)((WG) + (size_t)rr * 256 + kt * 64 + c8 * 8);        \
            }                                                                            \
            __syncthreads();                                                             \
            _Pragma("unroll") for (int kk = 0; kk < 2; ++kk) {                           \
                bf16x8 bfr[8];                                                           \
                _Pragma("unroll") for (int nt = 0; nt < 8; ++nt)                         \
                    bfr[nt] = *(const bf16x8*)&Ws[wc * 128 + nt * 16 + lo][kk * 32 + hi * 8]; \
                const bf16x8 afr = *(const bf16x8*)&BUF[kt][wr * 16 + lo][kk * 32 + hi * 8]; \
                _Pragma("unroll") for (int nt = 0; nt < 8; ++nt)                         \
                    acc[nt] = __builtin_amdgcn_mfma_f32_16x16x32_bf16(afr, bfr[nt], acc[nt], 0, 0, 0); \
            }                                                                            \
            __syncthreads();                                                             \
        }                                                                                \
    }

    // ---- Stage 1: out_proj + bias + X residual + LN1 -> X1 (Xbuf) ----
    STAGE_K256(Abuf, Wo)
    {
        float bi[8], gg[8], bb[8];
        #pragma unroll
        for (int nt = 0; nt < 8; ++nt) {
            const int col = wc * 128 + nt * 16 + lo;
            bi[nt] = bo[col]; gg[nt] = g1[col]; bb[nt] = be1[col];
        }
        #pragma unroll
        for (int r = 0; r < 4; ++r) {
            const int rl = wr * 16 + hi * 4 + r;
            const size_t grow = (size_t)(m0 + rl) * DMODEL;
            float s = 0.f, q = 0.f;
            #pragma unroll
            for (int nt = 0; nt < 8; ++nt) {
                const int col = wc * 128 + nt * 16 + lo;
                float v = acc[nt][r] + bi[nt] + bf2f(X[grow + col]);
                acc[nt][r] = v;
                s += v; q += v * v;
            }
            #pragma unroll
            for (int o = 1; o < 16; o <<= 1) { s += __shfl_xor(s, o); q += __shfl_xor(q, o); }
            if (lo == 0) { rsum[rl][wc] = s; rsq[rl][wc] = q; }
        }
        __syncthreads();
        #pragma unroll
        for (int r = 0; r < 4; ++r) {
            const int rl = wr * 16 + hi * 4 + r;
            const float mean = (rsum[rl][0] + rsum[rl][1]) * (1.f / DMODEL);
            const float var = (rsq[rl][0] + rsq[rl][1]) * (1.f / DMODEL) - mean * mean;
            const float rstd = rsqrtf(var + 1e-5f);
            #pragma unroll
            for (int nt = 0; nt < 8; ++nt) {
                const int col = wc * 128 + nt * 16 + lo;
                Xbuf[col >> 6][rl][col & 63] = f2bf((acc[nt][r] - mean) * rstd * gg[nt] + bb[nt]);
            }
        }
    }
    __syncthreads();

    // ---- Stage 2: ff1 + bias + relu -> FFH (over Abuf) ----
    STAGE_K256(Xbuf, W1)
    {
        #pragma unroll
        for (int nt = 0; nt < 8; ++nt) {
            const int col = wc * 128 + nt * 16 + lo;
            const float bi = bF1[col];
            #pragma unroll
            for (int r = 0; r < 4; ++r) {
                const int rl = wr * 16 + hi * 4 + r;
                Abuf[col >> 6][rl][col & 63] = f2bf(fmaxf(acc[nt][r] + bi, 0.f));
            }
        }
    }
    __syncthreads();

    // ---- Stage 3: ff2 + bias + X1 residual + LN2 -> X2 (in-place over Xbuf) ----
    STAGE_K256(Abuf, W2)
    {
        float bi[8], gg[8], bb[8];
        #pragma unroll
        for (int nt = 0; nt < 8; ++nt) {
            const int col = wc * 128 + nt * 16 + lo;
            bi[nt] = bF2[col]; gg[nt] = g2[col]; bb[nt] = be2[col];
        }
        #pragma unroll
        for (int r = 0; r < 4; ++r) {
            const int rl = wr * 16 + hi * 4 + r;
            float s = 0.f, q = 0.f;
            #pragma unroll
            for (int nt = 0; nt < 8; ++nt) {
                const int col = wc * 128 + nt * 16 + lo;
                float v = acc[nt][r] + bi[nt] + bf2f(Xbuf[col >> 6][rl][col & 63]);
                acc[nt][r] = v;
                s += v; q += v * v;
            }
            #pragma unroll
            for (int o = 1; o < 16; o <<= 1) { s += __shfl_xor(s, o); q += __shfl_xor(q, o); }
            if (lo == 0) { rsum[rl][wc] = s; rsq[rl][wc] = q; }
        }
        __syncthreads();   // all X1 residual reads done before any X2 write
        #pragma unroll
        for (int r = 0; r < 4; ++r) {
            const int rl = wr * 16 + hi * 4 + r;
            const float mean = (rsum[rl][0] + rsum[rl][1]) * (1.f / DMODEL);
            const float var = (rsq[rl][0] + rsq[rl][1]) * (1.f / DMODEL) - mean * mean;
            const float rstd = rsqrtf(var + 1e-5f);
            #pragma unroll
            for (int nt = 0; nt < 8; ++nt) {
                const int col = wc * 128 + nt * 16 + lo;
                Xbuf[col >> 6][rl][col & 63] = f2bf((acc[nt][r] - mean) * rstd * gg[nt] + bb[nt]);
            }
        }
    }
    __syncthreads();

    // ---- Stage 4: dec (N=64) from X2 -> fp32 out ----
    {
        f32x4 acc2[2];
        #pragma unroll
        for (int nt = 0; nt < 2; ++nt) acc2[nt] = (f32x4){0.f, 0.f, 0.f, 0.f};
        for (int kt = 0; kt < 4; ++kt) {
            #pragma unroll
            for (int l = 0; l < 2; ++l) {
                const int s = tid + 256 * l;
                const int rr = s >> 3, c8 = s & 7;
                *(bf16x8*)&Ws[rr][c8 * 8] = *(const bf16x8*)(Wd + (size_t)rr * 256 + kt * 64 + c8 * 8);
            }
            __syncthreads();
            #pragma unroll
            for (int kk = 0; kk < 2; ++kk) {
                bf16x8 bfr[2];
                #pragma unroll
                for (int nt = 0; nt < 2; ++nt)
                    bfr[nt] = *(const bf16x8*)&Ws[wc * 32 + nt * 16 + lo][kk * 32 + hi * 8];
                const bf16x8 afr = *(const bf16x8*)&Xbuf[kt][wr * 16 + lo][kk * 32 + hi * 8];
                #pragma unroll
                for (int nt = 0; nt < 2; ++nt)
                    acc2[nt] = __builtin_amdgcn_mfma_f32_16x16x32_bf16(afr, bfr[nt], acc2[nt], 0, 0, 0);
            }
            __syncthreads();
        }
        #pragma unroll
        for (int nt = 0; nt < 2; ++nt) {
            const int col = wc * 32 + nt * 16 + lo;
            const float bi = bd[col];
            #pragma unroll
            for (int r = 0; r < 4; ++r) {
                const int row = m0 + wr * 16 + hi * 4 + r;
                out[(size_t)row * OUTSZ + col] = acc2[nt][r] + bi;
            }
        }
    }
    #undef STAGE_K256
}

// ---------------------------------------------------------------------------
// MFMA banded attention, bf16 I/O (unchanged from round 12, measured good).
// ---------------------------------------------------------------------------
__global__ __launch_bounds__(256, 3) void attn_mfma_kernel(const short* __restrict__ qkv,
                                                           short* __restrict__ ctx,
                                                           const int* __restrict__ nptr) {
    __shared__ short KV[160 * 128];
    __shared__ short QP[32 * 160];
    __shared__ float redmax[2][32];
    __shared__ float redsum[2][32];

    const int tid = threadIdx.x;
    const int bid = xcd_swizzle(blockIdx.x, gridDim.x);
    const int tile = bid % NQT;
    const int bh = bid / NQT;
    const int h = bh & (NHEAD - 1);
    const int b = bh >> 1;
    const int NN = *nptr;               // 100
    const int i0 = tile * TQ;
    const int klo = max(0, i0 - NN);
    const size_t base = (size_t)b * SEQ * 768;

    const int lane = tid & 63;
    const int wid = tid >> 6;
    const int lo = lane & 15;
    const int hi = lane >> 4;
    const int wm = wid >> 1;
    const int wn = wid & 1;

    #pragma unroll
    for (int l = 0; l < 10; ++l) {
        const int s = tid + 256 * l;
        const int r = s >> 4;
        const int c8 = s & 15;
        const int j = min(klo + r, SEQ - 1);
        const bf16x8 v = *(const bf16x8*)(qkv + base + (size_t)j * 768 + DMODEL + h * HDIM + c8 * 8);
        *(bf16x8*)&KV[(r * 128 + c8 * 8) ^ ((r & 7) << 3)] = v;
    }
    #pragma unroll
    for (int l = 0; l < 2; ++l) {
        const int s = tid + 256 * l;
        const int r = s >> 4;
        const int c8 = s & 15;
        const int qi = min(i0 + r, SEQ - 1);
        const bf16x8 v = *(const bf16x8*)(qkv + base + (size_t)qi * 768 + h * HDIM + c8 * 8);
        *(bf16x8*)&QP[(r * 128 + c8 * 8) ^ ((r & 7) << 3)] = v;
    }
    __syncthreads();   // bar0

    f32x4 sacc[5];
    #pragma unroll
    for (int mf = 0; mf < 5; ++mf) sacc[mf] = (f32x4){0.f, 0.f, 0.f, 0.f};
    #pragma unroll
    for (int ks = 0; ks < 4; ++ks) {
        const int qrow = wn * 16 + lo;
        const bf16x8 qf = *(const bf16x8*)&QP[(qrow * 128 + ks * 32 + hi * 8) ^ ((qrow & 7) << 3)];
        #pragma unroll
        for (int mf = 0; mf < 5; ++mf) {
            const int krow = wm * 80 + mf * 16 + lo;
            const bf16x8 kf = *(const bf16x8*)&KV[(krow * 128 + ks * 32 + hi * 8) ^ ((krow & 7) << 3)];
            sacc[mf] = __builtin_amdgcn_mfma_f32_16x16x32_bf16(kf, qf, sacc[mf], 0, 0, 0);
        }
    }

    const int qq = wn * 16 + lo;
    const int qi = i0 + qq;
    float mxw = -3.4e38f;
    #pragma unroll
    for (int mf = 0; mf < 5; ++mf)
        #pragma unroll
        for (int r = 0; r < 4; ++r) {
            const int ja = klo + wm * 80 + mf * 16 + hi * 4 + r;
            const bool ok = (ja >= qi - NN) && (ja <= qi);
            sacc[mf][r] = ok ? sacc[mf][r] : -3.4e38f;
            mxw = fmaxf(mxw, sacc[mf][r]);
        }
    mxw = fmaxf(mxw, __shfl_xor(mxw, 16));
    mxw = fmaxf(mxw, __shfl_xor(mxw, 32));
    mxw = fmaxf(mxw, -1e30f);
    float sml = 0.f;
    #pragma unroll
    for (int mf = 0; mf < 5; ++mf)
        #pragma unroll
        for (int r = 0; r < 4; ++r) {
            const float p = expf(sacc[mf][r] - mxw);
            sacc[mf][r] = p;
            sml += p;
        }
    sml += __shfl_xor(sml, 16);
    sml += __shfl_xor(sml, 32);
    if (hi == 0) { redmax[wm][qq] = mxw; redsum[wm][qq] = sml; }
    __syncthreads();   // bar1

    #pragma unroll
    for (int l = 0; l < 10; ++l) {
        const int s = tid + 256 * l;
        const int r = s >> 4;
        const int c8 = s & 15;
        const int j = min(klo + r, SEQ - 1);
        const bf16x8 v = *(const bf16x8*)(qkv + base + (size_t)j * 768 + 2 * DMODEL + h * HDIM + c8 * 8);
        *(bf16x8*)&KV[(r * 128 + c8 * 8) ^ (((r >> 3) & 3) << 4)] = v;
    }

    {
        const float m0 = redmax[0][qq], m1 = redmax[1][qq];
        const float mx = fmaxf(m0, m1);
        const float tot = redsum[0][qq] * expf(m0 - mx) + redsum[1][qq] * expf(m1 - mx);
        const float fac = expf(mxw - mx) / tot;
        #pragma unroll
        for (int mf = 0; mf < 5; ++mf)
            #pragma unroll
            for (int r = 0; r < 4; ++r) {
                const int key = wm * 80 + mf * 16 + hi * 4 + r;
                QP[(qq * 160 + key) ^ ((qq & 3) << 3)] = f2bf(sacc[mf][r] * fac);
            }
    }
    __syncthreads();   // bar2

    f32x4 oacc[2][2];
    #pragma unroll
    for (int mf = 0; mf < 2; ++mf)
        #pragma unroll
        for (int nf = 0; nf < 2; ++nf) oacc[mf][nf] = (f32x4){0.f, 0.f, 0.f, 0.f};
    const int dimb = wid * 32;
    #pragma unroll
    for (int ksp = 0; ksp < 5; ++ksp) {
        bf16x8 vf0, vf1;
        #pragma unroll
        for (int j = 0; j < 8; ++j) {
            const int key = ksp * 32 + hi * 8 + j;
            const int x = ((key >> 3) & 3) << 4;
            vf0[j] = KV[(key * 128 + dimb + lo) ^ x];
            vf1[j] = KV[(key * 128 + dimb + 16 + lo) ^ x];
        }
        #pragma unroll
        for (int mf = 0; mf < 2; ++mf) {
            const int prow = mf * 16 + lo;
            const bf16x8 pf = *(const bf16x8*)&QP[(prow * 160 + ksp * 32 + hi * 8) ^ ((prow & 3) << 3)];
            oacc[mf][0] = __builtin_amdgcn_mfma_f32_16x16x32_bf16(pf, vf0, oacc[mf][0], 0, 0, 0);
            oacc[mf][1] = __builtin_amdgcn_mfma_f32_16x16x32_bf16(pf, vf1, oacc[mf][1], 0, 0, 0);
        }
    }
    #pragma unroll
    for (int mf = 0; mf < 2; ++mf)
        #pragma unroll
        for (int r = 0; r < 4; ++r) {
            const int q = mf * 16 + hi * 4 + r;
            if (i0 + q < SEQ) {
                short* dst = ctx + ((size_t)b * SEQ + i0 + q) * DMODEL + h * HDIM + dimb;
                dst[lo]      = f2bf(oacc[mf][0][r]);
                dst[16 + lo] = f2bf(oacc[mf][1][r]);
            }
        }
}

// ---------------------------------------------------------------------------
// Launch
// ---------------------------------------------------------------------------
extern "C" void kernel_launch(void* const* d_in, const int* in_sizes, int n_in,
                              void* d_out, int out_size, void* d_ws, size_t ws_size,
                              hipStream_t stream) {
    const float* src       = (const float*)d_in[0];
    const float* enc_w     = (const float*)d_in[1];
    const float* enc_b     = (const float*)d_in[2];
    const float* in_proj_w = (const float*)d_in[3];
    const float* in_proj_b = (const float*)d_in[4];
    const float* out_proj_w= (const float*)d_in[5];
    const float* out_proj_b= (const float*)d_in[6];
    const float* ln1_g     = (const float*)d_in[7];
    const float* ln1_b     = (const float*)d_in[8];
    const float* ff1_w     = (const float*)d_in[9];
    const float* ff1_b     = (const float*)d_in[10];
    const float* ff2_w     = (const float*)d_in[11];
    const float* ff2_b     = (const float*)d_in[12];
    const float* ln2_g     = (const float*)d_in[13];
    const float* ln2_b     = (const float*)d_in[14];
    const float* dec_w     = (const float*)d_in[15];
    const float* dec_b     = (const float*)d_in[16];
    const int*   nptr      = (const int*)d_in[17];

    // workspace layout (shorts for bf16 activations)
    short* SW   = (short*)d_ws;
    short* X    = SW;                   //  8,192,000 shorts (encode out)
    short* QKV  = SW + 8192000;         // 24,576,000
    short* CTX  = SW + 32768000;        //  8,192,000
    float* PE   = (float*)(SW + 49152000);   // 512,000 floats
    short* WB   = SW + 50176000;        //   442,368 shorts (bf16 weights)
    float* QKVB = (float*)(SW + 50618368);   // 768 floats (scaled qkv bias)
    float* OUT  = (float*)d_out;

    short* enc_wb  = WB;
    short* inp_wb  = WB + 32768;
    short* outp_wb = WB + 229376;
    short* ff1_wb  = WB + 294912;
    short* ff2_wb  = WB + 360448;
    short* dec_wb  = WB + 425984;

    // merged setup: PE (2000) + wconv (1728) + qkv bias (3)
    setup_kernel<<<SEQ + 1728 + 3, 256, 0, stream>>>(
        enc_w, in_proj_w, out_proj_w, ff1_w, ff2_w, dec_w, in_proj_b,
        PE, WB, QKVB);

    // encode: fp32 src -> bf16 X (+bias+pe)
    gemm_mfma_kernel<2, false><<<(MROWS / 128) * (DMODEL / 64), 256, 0, stream>>>(
        src, enc_wb, enc_b, PE, X, MROWS, DMODEL, INSZ, DMODEL / 64);
    // qkv
    gemm_mfma_kernel<0, true><<<(MROWS / 128) * ((3 * DMODEL) / 64), 256, 0, stream>>>(
        X, inp_wb, QKVB, nullptr, QKV, MROWS, 3 * DMODEL, DMODEL, (3 * DMODEL) / 64);
    // attention
    attn_mfma_kernel<<<BATCH * NHEAD * NQT, 256, 0, stream>>>(QKV, CTX, nptr);
    // fused tail: out_proj+LN1 -> ff1 -> ff2+LN2 -> dec
    tail_fused_kernel<<<MROWS / 32, 256, 0, stream>>>(
        CTX, X, outp_wb, out_proj_b, ln1_g, ln1_b,
        ff1_wb, ff1_b, ff2_wb, ff2_b, ln2_g, ln2_b,
        dec_wb, dec_b, OUT);
}